// Round 13
// baseline (1611.662 us; speedup 1.0000x reference)
//
#include <hip/hip_runtime.h>

typedef unsigned short u16;
typedef __attribute__((ext_vector_type(8))) short bf8;
typedef __attribute__((ext_vector_type(4))) short sh4;
typedef __attribute__((ext_vector_type(4))) float f4;

#define MFMA16(a,b,c) __builtin_amdgcn_mfma_f32_16x16x32_bf16((a),(b),(c),0,0,0)
#define SB() __builtin_amdgcn_sched_barrier(0)

__device__ __forceinline__ float bf2f(u16 u){ return __uint_as_float(((unsigned)u)<<16); }
__device__ __forceinline__ u16 f2bf(float f){
  unsigned u = __float_as_uint(f);
  u += 0x7fffu + ((u>>16)&1u);
  return (u16)(u>>16);
}
__device__ __forceinline__ float tanh_fast(float x){
  x = fminf(fmaxf(x, -15.f), 15.f);
  float e = __expf(2.f*x);
  return (e-1.f)/(e+1.f);
}
#define GELU_C 0.7978845608028654f
__device__ __forceinline__ float gelu_f(float x){
  float t = tanh_fast(GELU_C*(x + 0.044715f*x*x*x));
  return 0.5f*x*(1.f+t);
}
__device__ __forceinline__ float gelu_bwd_f(float x){
  float t = tanh_fast(GELU_C*(x + 0.044715f*x*x*x));
  return 0.5f*(1.f+t) + 0.5f*x*(1.f-t*t)*GELU_C*(1.f+0.134145f*x*x);
}

// Universal LDS swizzle: element (r,c) of a row-major [R][ldc] bf16 matrix.
__device__ __forceinline__ int IDX(int r, int c, int ldc){
  int f = ((r>>3) ^ r) & 7;
  return r*ldc + ((((c>>3) ^ f)<<3) | (c&7));
}

// ---------------------------------------------------------------- convert: build wcat in d_out scratch
__global__ void convert_kernel(const float* __restrict__ Wq, const float* __restrict__ Wk,
    const float* __restrict__ Wv, const float* __restrict__ lrw, u16* __restrict__ wcat)
{
  size_t i0 = (size_t)blockIdx.x*blockDim.x + threadIdx.x;
  size_t stride = (size_t)gridDim.x*blockDim.x;
  for (size_t i=i0; i<3276800u; i+=stride){
    int n = (int)(i>>10);
    float v;
    if (n < 1024) v = Wq[i];
    else if (n < 2048) v = Wk[i - 1048576u];
    else if (n < 3072) v = Wv[i - 2097152u];
    else if (n < 3088) v = lrw[i - 3145728u];
    else v = 0.f;
    wcat[i] = f2bf(v);
  }
}

// ---------------------------------------------------------------- GEMM  C[M,N] = A[M,K] @ B[N,K]^T
template<int AF32, int BF32, int COUT>
__global__ __launch_bounds__(256) void gemm_kernel(const void* __restrict__ Ap, const void* __restrict__ Bp,
    void* __restrict__ C, int M, int N, int K, int lda, int ldb, int ldc)
{
  __shared__ __align__(16) u16 sA[128*64];
  __shared__ __align__(16) u16 sB[128*64];
  const int tid = threadIdx.x;
  const int lane = tid & 63, wid = tid >> 6;
  const int lr = lane & 15, lg = lane >> 4;
  const int wm = wid >> 1, wn = wid & 1;
  const int m0 = blockIdx.y*128, n0 = blockIdx.x*128;
  f4 acc[4][4];
  #pragma unroll
  for (int mi=0;mi<4;++mi)
    #pragma unroll
    for (int ni=0;ni<4;++ni){ acc[mi][ni][0]=0.f; acc[mi][ni][1]=0.f; acc[mi][ni][2]=0.f; acc[mi][ni][3]=0.f; }
  for (int k0=0; k0<K; k0+=64){
    #pragma unroll
    for (int i=0;i<4;++i){
      int cid = i*256 + tid;
      int row = cid>>3, cc = cid&7;
      int sl = cc ^ (row&7);
      bf8 pa, pb;
      if (AF32){
        const float* p = (const float*)Ap + (size_t)(m0+row)*lda + k0 + cc*8;
        #pragma unroll
        for (int j=0;j<8;++j) pa[j] = (short)f2bf(p[j]);
      } else {
        pa = *(const bf8*)((const u16*)Ap + (size_t)(m0+row)*lda + k0 + cc*8);
      }
      if (BF32){
        const float* p = (const float*)Bp + (size_t)(n0+row)*ldb + k0 + cc*8;
        #pragma unroll
        for (int j=0;j<8;++j) pb[j] = (short)f2bf(p[j]);
      } else {
        pb = *(const bf8*)((const u16*)Bp + (size_t)(n0+row)*ldb + k0 + cc*8);
      }
      *(bf8*)&sA[row*64 + sl*8] = pa;
      *(bf8*)&sB[row*64 + sl*8] = pb;
    }
    __syncthreads();
    #pragma unroll
    for (int kc=0;kc<2;++kc){
      bf8 av[4], bv[4];
      #pragma unroll
      for (int i=0;i<4;++i){
        int ra = wm*64 + i*16 + lr;
        av[i] = *(const bf8*)&sA[ra*64 + ((kc*4+lg)^(ra&7))*8];
        int rb = wn*64 + i*16 + lr;
        bv[i] = *(const bf8*)&sB[rb*64 + ((kc*4+lg)^(rb&7))*8];
      }
      #pragma unroll
      for (int mi=0;mi<4;++mi)
        #pragma unroll
        for (int ni=0;ni<4;++ni)
          acc[mi][ni] = MFMA16(av[mi], bv[ni], acc[mi][ni]);
    }
    __syncthreads();
  }
  #pragma unroll
  for (int mi=0;mi<4;++mi)
    #pragma unroll
    for (int ni=0;ni<4;++ni)
      #pragma unroll
      for (int r=0;r<4;++r){
        int row = m0 + wm*64 + mi*16 + lg*4 + r;
        int col = n0 + wn*64 + ni*16 + lr;
        if (COUT) ((float*)C)[(size_t)row*ldc + col] = acc[mi][ni][r];
        else ((u16*)C)[(size_t)row*ldc + col] = f2bf(acc[mi][ni][r]);
      }
}

// ---------------------------------------------------------------- postprocess IN PLACE on qkvl rows
__global__ __launch_bounds__(1024) void postproc_kernel(
    u16* __restrict__ qkvl, const float* __restrict__ tnw, const float* __restrict__ tnb,
    const float* __restrict__ lrb, float* __restrict__ eto)
{
  int row = blockIdx.x;              // b*2048 + l
  int l = row & 2047;
  int h = threadIdx.x >> 6;
  int d = threadIdx.x & 63;
  u16* rp = qkvl + (size_t)row*3200;
  float q = bf2f(rp[h*64+d]);
  float k = bf2f(rp[1024 + h*64+d]);
  float v = bf2f(rp[2048 + h*64+d]);
  float nq = q*q, nk = k*k;
  #pragma unroll
  for (int off=1; off<64; off<<=1){ nq += __shfl_xor(nq, off); nk += __shfl_xor(nk, off); }
  q = q / fmaxf(sqrtf(nq), 1e-12f);
  k = k / fmaxf(sqrtf(nk), 1e-12f);
  int pos = l & 63;
  float invf = __expf((float)(d&31) * -0.2878231366f);   // ln(10000)/32
  float f = (float)pos * invf;
  float sn, cs; sincosf(f, &sn, &cs);
  float qp = __shfl_xor(q, 32), kp = __shfl_xor(k, 32);
  float qr = q*cs + ((d<32) ? -qp : qp)*sn;
  float kr = k*cs + ((d<32) ? -kp : kp)*sn;
  float dv = v - kr;
  float mu = dv;
  #pragma unroll
  for (int off=1; off<64; off<<=1) mu += __shfl_xor(mu, off);
  mu *= (1.f/64.f);
  float cdv = dv - mu;
  float s2 = cdv*cdv;
  #pragma unroll
  for (int off=1; off<64; off<<=1) s2 += __shfl_xor(s2, off);
  float sd = sqrtf(s2 * (1.f/63.f));
  float tgt = tnw[h*64+d]*cdv/(sd + 1e-8f) + tnb[h*64+d];
  float lgt = bf2f(rp[3072+h]) + lrb[h];
  rp[h*64+d]        = f2bf(qr);
  rp[1024 + h*64+d] = f2bf(kr);
  rp[2048 + h*64+d] = f2bf(tgt);
  if (d == 0)
    eto[(size_t)((row>>11)*16 + h)*2048 + l] = (1.f/(1.f+__expf(-lgt))) * (1.f/64.f);
}

// ---------------------------------------------------------------- TTT scan: one block per (b,h), 16 waves
// Masters bf16 in LDS (RMW-MFMA updates), anti-LICM opaque index copies (the R11
// fix: prevents hoisting+spilling of per-chunk LDS addresses), X2bp packing and
// late aq loads keep peak live set ~55 regs < the 64-VGPR budget at 1024 threads.
// 16 waves halve per-wave work and double waves/SIMD (2->4) vs the 512t version.
__global__ __launch_bounds__(1024) void scan_kernel(
    u16* __restrict__ qkvl, const float* __restrict__ etg,
    const float* __restrict__ W1g, const float* __restrict__ b1g,
    const float* __restrict__ W2g, const float* __restrict__ b2g,
    const float* __restrict__ tnw, const float* __restrict__ tnb)
{
  __shared__ __align__(16) u16 tW1[16384];   // [256 r=W1col][64 c=W1row]  W1^T swizzled, bf16 master
  __shared__ __align__(16) u16 tW2[16384];   // [64 r=W2col][256 c=W2row]  W2^T swizzled, bf16 master
  __shared__ __align__(16) u16 sX2[16384];   // [64][256]
  __shared__ __align__(16) u16 tG1[16384];   // [256][64] gZ1^T; reused as X2bar [64][256]
  __shared__ __align__(16) u16 sXk[4096];    // [64][64]
  __shared__ __align__(16) u16 tG2[4096];    // [64][64] gZ2^T
  __shared__ __align__(16) u16 sM[4096];     // [64][64]
  __shared__ float b1f[256];
  __shared__ float b2f[64];
  __shared__ float Et[64];
  __shared__ float gwv[64], gbv[64];
  __shared__ float st1[64][8];
  __shared__ float st2[64][8];

  const int tid0 = threadIdx.x;
  const int lr0 = tid0 & 15;
  const int lg0 = (tid0 & 63) >> 4;
  const int w0  = tid0 >> 6;    // 0..15
  const int mtw0 = w0 >> 2;     // 0..3 : 16-row tile
  const int ct0  = w0 & 3;      // 0..3 : col tile group
  const int bh = blockIdx.x;
  const int h = bh & 15;
  const int b = bh >> 4;
  const f4 ZV = {0.f, 0.f, 0.f, 0.f};

  if (tid0 < 64){ gwv[tid0] = tnw[h*64+tid0]; gbv[tid0] = tnb[h*64+tid0]; b2f[tid0] = b2g[h*64+tid0]; }
  if (tid0 < 256) b1f[tid0] = b1g[h*256+tid0];

  // masters (fp32 global) -> bf16 LDS images
  #pragma unroll
  for (int t=0;t<4;++t){
    sh4 p1, p2;
    #pragma unroll
    for (int r=0;r<4;++r){
      p1[r] = (short)f2bf(W1g[(size_t)h*16384 + (mtw0*16+lg0*4+r)*256 + (ct0*4+t)*16+lr0]);
      p2[r] = (short)f2bf(W2g[(size_t)h*16384 + ((ct0*4+t)*16+lg0*4+r)*64 + mtw0*16+lr0]);
    }
    *(sh4*)&tW1[IDX((ct0*4+t)*16+lr0, mtw0*16+lg0*4, 64)] = p1;
    *(sh4*)&tW2[IDX(mtw0*16+lr0, (ct0*4+t)*16+lg0*4, 256)] = p2;
  }
  __syncthreads();

  u16* qb = qkvl + (size_t)(b*2048)*3200 + h*64;
  const float* etb = etg + (size_t)bh*2048;

  for (int c=0; c<32; ++c){
    // Anti-LICM: every derived LDS/global address is loop-variant -> recomputed
    // per chunk (cheap VALU) instead of hoisted+spilled (the R10 pathology).
    int tid = tid0, lr = lr0, lg = lg0, mtw = mtw0, ct = ct0;
    asm volatile("" : "+v"(tid), "+v"(lr), "+v"(lg), "+v"(mtw), "+v"(ct));

    u16* xq = qb + (size_t)c*64*3200;
    const u16* xk = xq + 1024;
    const u16* tg = xq + 2048;
    u16* yrow = xq + 2048;

    if (tid < 512){ // stage xk (swizzled)
      int r = tid>>3, c0 = (tid&7)*8;
      bf8 vv = *(const bf8*)(xk + (size_t)r*3200 + c0);
      *(bf8*)&sXk[IDX(r, c0, 64)] = vv;
    }
    if (tid < 64) Et[tid] = etb[c*64 + tid];
    u16 tgp[4];
    #pragma unroll
    for (int r=0;r<4;++r)
      tgp[r] = tg[(size_t)(mtw*16+lg*4+r)*3200 + ct*16+lr];
    __syncthreads();
    SB();

    // ---- S1: Z1 = xk@W1 + b1 ; X2 = gelu(Z1) -> sX2   (Z1 recomputed in S3)
    {
      f4 acc1[4];
      #pragma unroll
      for (int t=0;t<4;++t) acc1[t] = ZV;
      #pragma unroll
      for (int kc=0; kc<2; ++kc){
        bf8 a = *(const bf8*)&sXk[IDX(mtw*16+lr, kc*32+lg*8, 64)];
        #pragma unroll
        for (int t=0;t<4;++t){
          bf8 bb = *(const bf8*)&tW1[IDX((ct*4+t)*16+lr, kc*32+lg*8, 64)];
          acc1[t] = MFMA16(a, bb, acc1[t]);
          if (t==1) SB();
        }
        SB();
      }
      #pragma unroll
      for (int t=0;t<4;++t){
        int col = (ct*4+t)*16 + lr;
        float bias = b1f[col];
        #pragma unroll
        for (int r=0;r<4;++r)
          sX2[IDX(mtw*16+lg*4+r, col, 256)] = f2bf(gelu_f(acc1[t][r] + bias));
        if (t==1) SB();
      }
    }
    __syncthreads();
    SB();

    // ---- S2: Z2 = X2@W2 + b2 ; layernorm-L2 backward -> tG2 (gZ2^T)
    f4 acc2 = ZV;
    #pragma unroll
    for (int kc=0; kc<8; ++kc){
      bf8 a = *(const bf8*)&sX2[IDX(mtw*16+lr, kc*32+lg*8, 256)];
      bf8 bb = *(const bf8*)&tW2[IDX(ct*16+lr, kc*32+lg*8, 256)];
      acc2 = MFMA16(a, bb, acc2);
      if (kc&1) SB();
    }
    SB();
    {
      float ps[4], pq[4];
      float bias0 = b2f[ct*16+lr];
      #pragma unroll
      for (int r=0;r<4;++r){
        acc2[r] += bias0;
        ps[r] = acc2[r];
        pq[r] = acc2[r]*acc2[r];
      }
      #pragma unroll
      for (int r=0;r<4;++r)
        #pragma unroll
        for (int off=1; off<16; off<<=1){ ps[r] += __shfl_xor(ps[r], off); pq[r] += __shfl_xor(pq[r], off); }
      if (lr == 0){
        #pragma unroll
        for (int r=0;r<4;++r){ st1[mtw*16+lg*4+r][ct*2] = ps[r]; st1[mtw*16+lg*4+r][ct*2+1] = pq[r]; }
      }
    }
    __syncthreads();
    SB();
    float gy[4], xh[4];
    {
      float pg[4], ph[4];
      int col = ct*16+lr;
      float g = gwv[col], bb = gbv[col];
      #pragma unroll
      for (int r=0;r<4;++r){
        int row = mtw*16+lg*4+r;
        float s1 = st1[row][0] + st1[row][2] + st1[row][4] + st1[row][6];
        float s2 = st1[row][1] + st1[row][3] + st1[row][5] + st1[row][7];
        float muv = s1 * (1.f/64.f);
        float rsv = rsqrtf(s2*(1.f/64.f) - muv*muv + 1e-6f);
        float x = (acc2[r] - muv) * rsv;
        float t = bf2f(tgp[r]);
        float gyv = (g*x + bb - t) * g;
        gy[r] = gyv; xh[r] = x;
        pg[r] = gyv; ph[r] = gyv*x;
      }
      #pragma unroll
      for (int r=0;r<4;++r)
        #pragma unroll
        for (int off=1; off<16; off<<=1){ pg[r] += __shfl_xor(pg[r], off); ph[r] += __shfl_xor(ph[r], off); }
      if (lr == 0){
        #pragma unroll
        for (int r=0;r<4;++r){ st2[mtw*16+lg*4+r][ct*2] = pg[r]; st2[mtw*16+lg*4+r][ct*2+1] = ph[r]; }
      }
    }
    __syncthreads();
    SB();
    {
      int col = ct*16+lr;
      sh4 pk;
      #pragma unroll
      for (int r=0;r<4;++r){
        int row = mtw*16+lg*4+r;
        float s1 = st1[row][0] + st1[row][2] + st1[row][4] + st1[row][6];
        float s2 = st1[row][1] + st1[row][3] + st1[row][5] + st1[row][7];
        float muv = s1 * (1.f/64.f);
        float rsv = rsqrtf(s2*(1.f/64.f) - muv*muv + 1e-6f);   // bit-identical recompute
        float sg = st2[row][0] + st2[row][2] + st2[row][4] + st2[row][6];
        float sx = st2[row][1] + st2[row][3] + st2[row][5] + st2[row][7];
        float gz = (64.f*gy[r] - sg - xh[r]*sx) * (rsv * (1.f/64.f));
        pk[r] = (short)f2bf(gz);
      }
      *(sh4*)&tG2[IDX(col, mtw*16+lg*4, 64)] = pk;
    }
    __syncthreads();
    SB();

    // ---- S3: gZ1 = (gZ2 @ W2^T) * gelu_bwd(Z1) -> tG1; Z1 recomputed bit-identically
    bf8 aq0, aq1;
    {
      f4 acc3[4];
      #pragma unroll
      for (int t=0;t<4;++t) acc3[t] = ZV;
      #pragma unroll
      for (int kc=0; kc<2; ++kc){
        int k0 = kc*32 + lg*8;
        bf8 a;
        #pragma unroll
        for (int j=0;j<8;++j) a[j] = (short)tG2[IDX(k0+j, mtw*16+lr, 64)];
        #pragma unroll
        for (int t=0;t<4;++t){
          bf8 bb;
          #pragma unroll
          for (int j=0;j<8;++j) bb[j] = (short)tW2[IDX(k0+j, (ct*4+t)*16+lr, 256)];
          acc3[t] = MFMA16(a, bb, acc3[t]);
          if (t==1) SB();
        }
        SB();
      }
      bf8 xk0 = *(const bf8*)&sXk[IDX(mtw*16+lr, 0*32+lg*8, 64)];
      bf8 xk1 = *(const bf8*)&sXk[IDX(mtw*16+lr, 1*32+lg*8, 64)];
      #pragma unroll
      for (int t=0;t<4;++t){
        int col = (ct*4+t)*16+lr;
        f4 z = ZV;
        z = MFMA16(xk0, *(const bf8*)&tW1[IDX(col, 0*32+lg*8, 64)], z);
        z = MFMA16(xk1, *(const bf8*)&tW1[IDX(col, 1*32+lg*8, 64)], z);
        float bias = b1f[col];
        sh4 pk;
        #pragma unroll
        for (int r=0;r<4;++r) pk[r] = (short)f2bf(acc3[t][r] * gelu_bwd_f(z[r] + bias));
        *(sh4*)&tG1[IDX(col, mtw*16+lg*4, 64)] = pk;
        if (t==1) SB();
      }
      SB();
      // late-issue xq fragment loads (first use: S4, next region)
      aq0 = *(const bf8*)(xq + (size_t)(mtw*16+lr)*3200 + lg*8);
      aq1 = *(const bf8*)(xq + (size_t)(mtw*16+lr)*3200 + 32 + lg*8);
    }
    __syncthreads();
    SB();

    // ---- S4: Attn1 = tril(xq@xk^T) -> M1 -> sM
    {
      f4 accA = ZV;
      accA = MFMA16(aq0, *(const bf8*)&sXk[IDX(ct*16+lr, 0*32+lg*8, 64)], accA);
      accA = MFMA16(aq1, *(const bf8*)&sXk[IDX(ct*16+lr, 1*32+lg*8, 64)], accA);
      SB();
      int col = ct*16+lr;
      float e = Et[col];
      #pragma unroll
      for (int r=0;r<4;++r){
        int row = mtw*16+lg*4+r;
        float m = (col <= row) ? (-e * (accA[r] + 1.f)) : 0.f;
        sM[IDX(row, col, 64)] = f2bf(m);
      }
    }
    __syncthreads();
    SB();

    // ---- S6': W1n = tW1(old, C from LDS) + (-eta*xk)^T @ gZ1 ; b1 colsum via Et-broadcast MFMA
    f4 W1n[4]; float b1d[4];
    #pragma unroll
    for (int t=0;t<4;++t){
      sh4 cf = *(const sh4*)&tW1[IDX((ct*4+t)*16+lr, mtw*16+lg*4, 64)];
      #pragma unroll
      for (int r=0;r<4;++r) W1n[t][r] = bf2f((u16)cf[r]);
    }
    SB();
    #pragma unroll
    for (int kc=0; kc<2; ++kc){
      int k0 = kc*32 + lg*8;
      bf8 xa, ea;
      #pragma unroll
      for (int j=0;j<8;++j){
        float e = Et[k0+j];
        ea[j] = (short)f2bf(e);
        xa[j] = (short)f2bf(-bf2f(sXk[IDX(k0+j, mtw*16+lr, 64)]) * e);
      }
      #pragma unroll
      for (int t=0;t<4;++t){
        bf8 bb = *(const bf8*)&tG1[IDX((ct*4+t)*16+lr, kc*32+lg*8, 64)];
        W1n[t] = MFMA16(xa, bb, W1n[t]);
        f4 d0 = ZV;
        d0 = MFMA16(ea, bb, d0);
        if (kc==0) b1d[t] = d0[0]; else b1d[t] += d0[0];
        if (t==1) SB();
      }
      SB();
    }
    // ---- S5: Z1_bar = xq@W1(old) + M1@gZ1 + b1 ; pack X2_bar bf16 immediately
    sh4 X2bp[4];
    {
      f4 acc4[4];
      #pragma unroll
      for (int t=0;t<4;++t) acc4[t] = ZV;
      #pragma unroll
      for (int kc=0; kc<2; ++kc){
        bf8 a = kc ? aq1 : aq0;
        #pragma unroll
        for (int t=0;t<4;++t){
          bf8 bb = *(const bf8*)&tW1[IDX((ct*4+t)*16+lr, kc*32+lg*8, 64)];
          acc4[t] = MFMA16(a, bb, acc4[t]);
          if (t==1) SB();
        }
        SB();
      }
      #pragma unroll
      for (int kc=0; kc<2; ++kc){
        bf8 a = *(const bf8*)&sM[IDX(mtw*16+lr, kc*32+lg*8, 64)];
        #pragma unroll
        for (int t=0;t<4;++t){
          bf8 bb = *(const bf8*)&tG1[IDX((ct*4+t)*16+lr, kc*32+lg*8, 64)];
          acc4[t] = MFMA16(a, bb, acc4[t]);
          if (t==1) SB();
        }
        SB();
      }
      #pragma unroll
      for (int t=0;t<4;++t){
        float bias = b1f[(ct*4+t)*16+lr];
        #pragma unroll
        for (int r=0;r<4;++r) X2bp[t][r] = (short)f2bf(gelu_f(acc4[t][r] + bias));
      }
    }
    __syncthreads();
    SB();
    // commit new W1 (bf16), write X2_bar over tG1, apply b1 delta
    u16* X2b = tG1;
    #pragma unroll
    for (int t=0;t<4;++t){
      int col = (ct*4+t)*16+lr;
      sh4 p1;
      #pragma unroll
      for (int r=0;r<4;++r){
        X2b[IDX(mtw*16+lg*4+r, col, 256)] = (u16)X2bp[t][r];
        p1[r] = (short)f2bf(W1n[t][r]);
      }
      *(sh4*)&tW1[IDX(col, mtw*16+lg*4, 64)] = p1;
      if (t==1) SB();
    }
    if (mtw == 0 && lg == 0){
      #pragma unroll
      for (int t=0;t<4;++t) b1f[(ct*4+t)*16+lr] -= b1d[t];
    }
    __syncthreads();
    SB();

    // ---- S7: Attn2 = tril(X2_bar @ X2^T) -> M2 -> sM
    {
      f4 accB = ZV;
      #pragma unroll
      for (int kc=0; kc<8; ++kc){
        bf8 a = *(const bf8*)&X2b[IDX(mtw*16+lr, kc*32+lg*8, 256)];
        bf8 bb = *(const bf8*)&sX2[IDX(ct*16+lr, kc*32+lg*8, 256)];
        accB = MFMA16(a, bb, accB);
        if (kc&1) SB();
      }
      SB();
      int col = ct*16+lr;
      float e = Et[col];
      #pragma unroll
      for (int r=0;r<4;++r){
        int row = mtw*16+lg*4+r;
        float m = (col <= row) ? (-e * (accB[r] + 1.f)) : 0.f;
        sM[IDX(row, col, 64)] = f2bf(m);
      }
    }
    __syncthreads();
    SB();

    // ---- S8: Z2_bar = X2_bar@W2 + M2@gZ2 + b2 (acc6)
    f4 acc6 = ZV;
    #pragma unroll
    for (int kc=0; kc<8; ++kc){
      bf8 a = *(const bf8*)&X2b[IDX(mtw*16+lr, kc*32+lg*8, 256)];
      bf8 bb = *(const bf8*)&tW2[IDX(ct*16+lr, kc*32+lg*8, 256)];
      acc6 = MFMA16(a, bb, acc6);
      if (kc&1) SB();
    }
    SB();
    #pragma unroll
    for (int kc=0; kc<2; ++kc){
      bf8 a = *(const bf8*)&sM[IDX(mtw*16+lr, kc*32+lg*8, 64)];
      bf8 bb = *(const bf8*)&tG2[IDX(ct*16+lr, kc*32+lg*8, 64)];
      acc6 = MFMA16(a, bb, acc6);
      SB();
    }
    {
      float bias0 = b2f[ct*16+lr];
      #pragma unroll
      for (int r=0;r<4;++r) acc6[r] += bias0;
    }
    SB();
    // ---- S9': W2n = tW2(old) + (-eta*X2)^T @ gZ2 ; b2 colsum via Et-broadcast MFMA
    f4 W2n[4]; float b2d;
    #pragma unroll
    for (int t=0;t<4;++t){
      sh4 cf = *(const sh4*)&tW2[IDX(mtw*16+lr, (ct*4+t)*16+lg*4, 256)];
      #pragma unroll
      for (int r=0;r<4;++r) W2n[t][r] = bf2f((u16)cf[r]);
    }
    SB();
    {
      f4 d = ZV;
      #pragma unroll
      for (int kc=0; kc<2; ++kc){
        int k0 = kc*32+lg*8;
        bf8 ea;
        #pragma unroll
        for (int j=0;j<8;++j) ea[j] = (short)f2bf(Et[k0+j]);
        bf8 bb = *(const bf8*)&tG2[IDX(ct*16+lr, kc*32+lg*8, 64)];
        d = MFMA16(ea, bb, d);
      }
      b2d = d[0];
    }
    SB();
    #pragma unroll
    for (int kc=0; kc<2; ++kc){
      int k0 = kc*32 + lg*8;
      bf8 bbB = *(const bf8*)&tG2[IDX(mtw*16+lr, kc*32+lg*8, 64)];
      #pragma unroll
      for (int t=0;t<4;++t){
        bf8 xa;
        #pragma unroll
        for (int j=0;j<8;++j) xa[j] = (short)f2bf(-bf2f(sX2[IDX(k0+j, (ct*4+t)*16+lr, 256)]) * Et[k0+j]);
        W2n[t] = MFMA16(xa, bbB, W2n[t]);
        if (t==1) SB();
      }
      SB();
    }
    __syncthreads();
    SB();
    // commit new W2, apply b2 delta, LN-fwd stats of Z2_bar
    #pragma unroll
    for (int t=0;t<4;++t){
      sh4 p2;
      #pragma unroll
      for (int r=0;r<4;++r) p2[r] = (short)f2bf(W2n[t][r]);
      *(sh4*)&tW2[IDX(mtw*16+lr, (ct*4+t)*16+lg*4, 256)] = p2;
      if (t==1) SB();
    }
    if (mtw == 0 && lg == 0) b2f[ct*16+lr] -= b2d;
    SB();
    {
      float ps[4], pq[4];
      #pragma unroll
      for (int r=0;r<4;++r){ ps[r] = acc6[r]; pq[r] = acc6[r]*acc6[r]; }
      #pragma unroll
      for (int r=0;r<4;++r)
        #pragma unroll
        for (int off=1; off<16; off<<=1){ ps[r] += __shfl_xor(ps[r], off); pq[r] += __shfl_xor(pq[r], off); }
      if (lr == 0){
        #pragma unroll
        for (int r=0;r<4;++r){ st1[mtw*16+lg*4+r][ct*2] = ps[r]; st1[mtw*16+lg*4+r][ct*2+1] = pq[r]; }
      }
    }
    __syncthreads();
    SB();
    // ---- S10: out = xq + ln_fwd(Z2_bar), bf16 over target columns (in place)
    #pragma unroll
    for (int r=0;r<4;++r){
      int row = mtw*16+lg*4+r;
      float s1 = st1[row][0] + st1[row][2] + st1[row][4] + st1[row][6];
      float s2 = st1[row][1] + st1[row][3] + st1[row][5] + st1[row][7];
      float m = s1 * (1.f/64.f);
      float rstd = rsqrtf(s2*(1.f/64.f) - m*m + 1e-6f);
      size_t ro = (size_t)row*3200;
      int col = ct*16+lr;
      float val = bf2f(xq[ro+col]) + gwv[col]*(acc6[r]-m)*rstd + gbv[col];
      yrow[ro+col] = f2bf(val);
    }
    __syncthreads();
  }
}

// ---------------------------------------------------------------- post layernorm over D=1024 (in place)
__global__ __launch_bounds__(256) void postln_kernel(u16* __restrict__ qkvl,
    const float* __restrict__ pw, const float* __restrict__ pb)
{
  int row = blockIdx.x;
  u16* rp = qkvl + (size_t)row*3200;
  float v[4]; float s1=0.f, s2=0.f;
  #pragma unroll
  for (int i=0;i<4;++i){ v[i] = bf2f(rp[2048 + threadIdx.x + i*256]); s1 += v[i]; s2 += v[i]*v[i]; }
  #pragma unroll
  for (int off=1; off<64; off<<=1){ s1 += __shfl_xor(s1, off); s2 += __shfl_xor(s2, off); }
  __shared__ float r1[4], r2[4];
  int w = threadIdx.x >> 6;
  if ((threadIdx.x & 63) == 0){ r1[w] = s1; r2[w] = s2; }
  __syncthreads();
  s1 = r1[0]+r1[1]+r1[2]+r1[3];
  s2 = r2[0]+r2[1]+r2[2]+r2[3];
  float mu = s1*(1.f/1024.f);
  float rstd = rsqrtf(s2*(1.f/1024.f) - mu*mu + 1e-6f);
  #pragma unroll
  for (int i=0;i<4;++i){
    int col = threadIdx.x + i*256;
    rp[col] = f2bf(pw[col]*(v[i]-mu)*rstd + pb[col]);
  }
}

// ---------------------------------------------------------------- launch
extern "C" void kernel_launch(void* const* d_in, const int* in_sizes, int n_in,
                              void* d_out, int out_size, void* d_ws, size_t ws_size,
                              hipStream_t stream)
{
  const float* x   = (const float*)d_in[0];
  const float* Wq  = (const float*)d_in[1];
  const float* Wk  = (const float*)d_in[2];
  const float* Wv  = (const float*)d_in[3];
  const float* Wo  = (const float*)d_in[4];
  const float* W1  = (const float*)d_in[5];
  const float* b1  = (const float*)d_in[6];
  const float* W2  = (const float*)d_in[7];
  const float* b2  = (const float*)d_in[8];
  const float* tnw = (const float*)d_in[9];
  const float* tnb = (const float*)d_in[10];
  const float* lrw = (const float*)d_in[11];
  const float* lrb = (const float*)d_in[12];
  const float* pnw = (const float*)d_in[13];
  const float* pnb = (const float*)d_in[14];
  (void)in_sizes; (void)n_in; (void)out_size; (void)ws_size;

  u16* qkvl  = (u16*)d_ws;                       // [8192][3200] bf16 = 50 MB
  u16* wcat  = (u16*)d_out;                      // d_out scratch; dead before final GEMM
  float* etg = (float*)((char*)d_out + 6553600);

  convert_kernel<<<1024, 256, 0, stream>>>(Wq, Wk, Wv, lrw, wcat);
  gemm_kernel<1,0,0><<<dim3(25, 64), 256, 0, stream>>>(x, wcat, qkvl, 8192, 3200, 1024, 1024, 1024, 3200);
  postproc_kernel<<<8192, 1024, 0, stream>>>(qkvl, tnw, tnb, lrb, etg);
  scan_kernel<<<64, 1024, 0, stream>>>(qkvl, etg, W1, b1, W2, b2, tnw, tnb);
  postln_kernel<<<8192, 256, 0, stream>>>(qkvl, pnw, pnb);
  gemm_kernel<0,1,1><<<dim3(8, 64), 256, 0, stream>>>(qkvl, Wo, d_out, 8192, 1024, 1024, 3200, 1024, 1024);
}

// Round 16
// 1096.939 us; speedup vs baseline: 1.4692x; 1.4692x over previous
//
#include <hip/hip_runtime.h>

typedef unsigned short u16;
typedef __attribute__((ext_vector_type(8))) short bf8;
typedef __attribute__((ext_vector_type(4))) short sh4;
typedef __attribute__((ext_vector_type(4))) float f4;

#define MFMA16(a,b,c) __builtin_amdgcn_mfma_f32_16x16x32_bf16((a),(b),(c),0,0,0)
#define SB() __builtin_amdgcn_sched_barrier(0)

__device__ __forceinline__ float bf2f(u16 u){ return __uint_as_float(((unsigned)u)<<16); }
__device__ __forceinline__ u16 f2bf(float f){
  unsigned u = __float_as_uint(f);
  u += 0x7fffu + ((u>>16)&1u);
  return (u16)(u>>16);
}
__device__ __forceinline__ float tanh_fast(float x){
  x = fminf(fmaxf(x, -15.f), 15.f);
  float e = __expf(2.f*x);
  return (e-1.f)/(e+1.f);
}
#define GELU_C 0.7978845608028654f
__device__ __forceinline__ float gelu_f(float x){
  float t = tanh_fast(GELU_C*(x + 0.044715f*x*x*x));
  return 0.5f*x*(1.f+t);
}
__device__ __forceinline__ float gelu_bwd_f(float x){
  float t = tanh_fast(GELU_C*(x + 0.044715f*x*x*x));
  return 0.5f*(1.f+t) + 0.5f*x*(1.f-t*t)*GELU_C*(1.f+0.134145f*x*x);
}

// Universal LDS swizzle: element (r,c) of a row-major [R][ldc] bf16 matrix.
__device__ __forceinline__ int IDX(int r, int c, int ldc){
  int f = ((r>>3) ^ r) & 7;
  return r*ldc + ((((c>>3) ^ f)<<3) | (c&7));
}

// ---------------------------------------------------------------- convert: build wcat in d_out scratch
__global__ void convert_kernel(const float* __restrict__ Wq, const float* __restrict__ Wk,
    const float* __restrict__ Wv, const float* __restrict__ lrw, u16* __restrict__ wcat)
{
  size_t i0 = (size_t)blockIdx.x*blockDim.x + threadIdx.x;
  size_t stride = (size_t)gridDim.x*blockDim.x;
  for (size_t i=i0; i<3276800u; i+=stride){
    int n = (int)(i>>10);
    float v;
    if (n < 1024) v = Wq[i];
    else if (n < 2048) v = Wk[i - 1048576u];
    else if (n < 3072) v = Wv[i - 2097152u];
    else if (n < 3088) v = lrw[i - 3145728u];
    else v = 0.f;
    wcat[i] = f2bf(v);
  }
}

// ---------------------------------------------------------------- GEMM  C[M,N] = A[M,K] @ B[N,K]^T
template<int AF32, int BF32, int COUT>
__global__ __launch_bounds__(256) void gemm_kernel(const void* __restrict__ Ap, const void* __restrict__ Bp,
    void* __restrict__ C, int M, int N, int K, int lda, int ldb, int ldc)
{
  __shared__ __align__(16) u16 sA[128*64];
  __shared__ __align__(16) u16 sB[128*64];
  const int tid = threadIdx.x;
  const int lane = tid & 63, wid = tid >> 6;
  const int lr = lane & 15, lg = lane >> 4;
  const int wm = wid >> 1, wn = wid & 1;
  const int m0 = blockIdx.y*128, n0 = blockIdx.x*128;
  f4 acc[4][4];
  #pragma unroll
  for (int mi=0;mi<4;++mi)
    #pragma unroll
    for (int ni=0;ni<4;++ni){ acc[mi][ni][0]=0.f; acc[mi][ni][1]=0.f; acc[mi][ni][2]=0.f; acc[mi][ni][3]=0.f; }
  for (int k0=0; k0<K; k0+=64){
    #pragma unroll
    for (int i=0;i<4;++i){
      int cid = i*256 + tid;
      int row = cid>>3, cc = cid&7;
      int sl = cc ^ (row&7);
      bf8 pa, pb;
      if (AF32){
        const float* p = (const float*)Ap + (size_t)(m0+row)*lda + k0 + cc*8;
        #pragma unroll
        for (int j=0;j<8;++j) pa[j] = (short)f2bf(p[j]);
      } else {
        pa = *(const bf8*)((const u16*)Ap + (size_t)(m0+row)*lda + k0 + cc*8);
      }
      if (BF32){
        const float* p = (const float*)Bp + (size_t)(n0+row)*ldb + k0 + cc*8;
        #pragma unroll
        for (int j=0;j<8;++j) pb[j] = (short)f2bf(p[j]);
      } else {
        pb = *(const bf8*)((const u16*)Bp + (size_t)(n0+row)*ldb + k0 + cc*8);
      }
      *(bf8*)&sA[row*64 + sl*8] = pa;
      *(bf8*)&sB[row*64 + sl*8] = pb;
    }
    __syncthreads();
    #pragma unroll
    for (int kc=0;kc<2;++kc){
      bf8 av[4], bv[4];
      #pragma unroll
      for (int i=0;i<4;++i){
        int ra = wm*64 + i*16 + lr;
        av[i] = *(const bf8*)&sA[ra*64 + ((kc*4+lg)^(ra&7))*8];
        int rb = wn*64 + i*16 + lr;
        bv[i] = *(const bf8*)&sB[rb*64 + ((kc*4+lg)^(rb&7))*8];
      }
      #pragma unroll
      for (int mi=0;mi<4;++mi)
        #pragma unroll
        for (int ni=0;ni<4;++ni)
          acc[mi][ni] = MFMA16(av[mi], bv[ni], acc[mi][ni]);
    }
    __syncthreads();
  }
  #pragma unroll
  for (int mi=0;mi<4;++mi)
    #pragma unroll
    for (int ni=0;ni<4;++ni)
      #pragma unroll
      for (int r=0;r<4;++r){
        int row = m0 + wm*64 + mi*16 + lg*4 + r;
        int col = n0 + wn*64 + ni*16 + lr;
        if (COUT) ((float*)C)[(size_t)row*ldc + col] = acc[mi][ni][r];
        else ((u16*)C)[(size_t)row*ldc + col] = f2bf(acc[mi][ni][r]);
      }
}

// ---------------------------------------------------------------- postprocess IN PLACE on qkvl rows
__global__ __launch_bounds__(1024) void postproc_kernel(
    u16* __restrict__ qkvl, const float* __restrict__ tnw, const float* __restrict__ tnb,
    const float* __restrict__ lrb, float* __restrict__ eto)
{
  int row = blockIdx.x;              // b*2048 + l
  int l = row & 2047;
  int h = threadIdx.x >> 6;
  int d = threadIdx.x & 63;
  u16* rp = qkvl + (size_t)row*3200;
  float q = bf2f(rp[h*64+d]);
  float k = bf2f(rp[1024 + h*64+d]);
  float v = bf2f(rp[2048 + h*64+d]);
  float nq = q*q, nk = k*k;
  #pragma unroll
  for (int off=1; off<64; off<<=1){ nq += __shfl_xor(nq, off); nk += __shfl_xor(nk, off); }
  q = q / fmaxf(sqrtf(nq), 1e-12f);
  k = k / fmaxf(sqrtf(nk), 1e-12f);
  int pos = l & 63;
  float invf = __expf((float)(d&31) * -0.2878231366f);   // ln(10000)/32
  float f = (float)pos * invf;
  float sn, cs; sincosf(f, &sn, &cs);
  float qp = __shfl_xor(q, 32), kp = __shfl_xor(k, 32);
  float qr = q*cs + ((d<32) ? -qp : qp)*sn;
  float kr = k*cs + ((d<32) ? -kp : kp)*sn;
  float dv = v - kr;
  float mu = dv;
  #pragma unroll
  for (int off=1; off<64; off<<=1) mu += __shfl_xor(mu, off);
  mu *= (1.f/64.f);
  float cdv = dv - mu;
  float s2 = cdv*cdv;
  #pragma unroll
  for (int off=1; off<64; off<<=1) s2 += __shfl_xor(s2, off);
  float sd = sqrtf(s2 * (1.f/63.f));
  float tgt = tnw[h*64+d]*cdv/(sd + 1e-8f) + tnb[h*64+d];
  float lgt = bf2f(rp[3072+h]) + lrb[h];
  rp[h*64+d]        = f2bf(qr);
  rp[1024 + h*64+d] = f2bf(kr);
  rp[2048 + h*64+d] = f2bf(tgt);
  if (d == 0)
    eto[(size_t)((row>>11)*16 + h)*2048 + l] = (1.f/(1.f+__expf(-lgt))) * (1.f/64.f);
}

// ---------------------------------------------------------------- TTT scan: one block per (b,h), 8 waves
// R11 configuration (512t / 128 VGPR, masters bf16 in LDS, anti-LICM opaque index
// copies — the proven no-spill operating point). R14 delta: sched_barrier(0) only
// at phase/sub-stage seams (not inside MFMA loops) so the scheduler can pipeline
// LDS loads within a phase.
__global__ __launch_bounds__(512) void scan_kernel(
    u16* __restrict__ qkvl, const float* __restrict__ etg,
    const float* __restrict__ W1g, const float* __restrict__ b1g,
    const float* __restrict__ W2g, const float* __restrict__ b2g,
    const float* __restrict__ tnw, const float* __restrict__ tnb)
{
  __shared__ __align__(16) u16 tW1[16384];   // [256][64] W1^T swizzled, bf16 master
  __shared__ __align__(16) u16 tW2[16384];   // [64][256] W2^T swizzled, bf16 master
  __shared__ __align__(16) u16 sX2[16384];   // [64][256]
  __shared__ __align__(16) u16 tG1[16384];   // [256][64] gZ1^T; reused as X2bar [64][256]
  __shared__ __align__(16) u16 sXk[4096];    // [64][64]
  __shared__ __align__(16) u16 tG2[4096];    // [64][64] gZ2^T
  __shared__ __align__(16) u16 sM[4096];     // [64][64]
  __shared__ float b1f[256];
  __shared__ float b2f[64];
  __shared__ float Et[64];
  __shared__ float gwv[64], gbv[64];
  __shared__ float st1[64][4];
  __shared__ float st2[64][4];

  const int tid0 = threadIdx.x;
  const int lr0 = tid0 & 15;
  const int lg0 = (tid0 & 63) >> 4;
  const int wid0 = tid0 >> 6;   // 0..7
  const int mtw0 = wid0 >> 1;   // 0..3
  const int nw0  = wid0 & 1;    // 0..1
  const int bh = blockIdx.x;
  const int h = bh & 15;
  const int b = bh >> 4;
  const f4 ZV = {0.f, 0.f, 0.f, 0.f};

  if (tid0 < 64){ gwv[tid0] = tnw[h*64+tid0]; gbv[tid0] = tnb[h*64+tid0]; b2f[tid0] = b2g[h*64+tid0]; }
  if (tid0 < 256) b1f[tid0] = b1g[h*256+tid0];

  #pragma unroll
  for (int t=0;t<8;++t){
    sh4 p1, p2;
    #pragma unroll
    for (int r=0;r<4;++r){
      p1[r] = (short)f2bf(W1g[(size_t)h*16384 + (mtw0*16+lg0*4+r)*256 + (nw0*8+t)*16+lr0]);
      p2[r] = (short)f2bf(W2g[(size_t)h*16384 + ((2*wid0+(t&1))*16+lg0*4+r)*64 + (t>>1)*16+lr0]);
    }
    *(sh4*)&tW1[IDX((nw0*8+t)*16+lr0, mtw0*16+lg0*4, 64)] = p1;
    *(sh4*)&tW2[IDX((t>>1)*16+lr0, (2*wid0+(t&1))*16+lg0*4, 256)] = p2;
  }
  __syncthreads();

  u16* qb = qkvl + (size_t)(b*2048)*3200 + h*64;
  const float* etb = etg + (size_t)bh*2048;

  for (int c=0; c<32; ++c){
    // Anti-LICM: every derived LDS/global address is loop-variant -> recomputed
    // per chunk (cheap VALU) instead of hoisted+spilled (the R10 pathology).
    int tid = tid0, lr = lr0, lg = lg0, mtw = mtw0, nw = nw0, wid = wid0;
    asm volatile("" : "+v"(tid), "+v"(lr), "+v"(lg), "+v"(mtw), "+v"(nw), "+v"(wid));

    u16* xq = qb + (size_t)c*64*3200;
    const u16* xk = xq + 1024;
    const u16* tg = xq + 2048;
    u16* yrow = xq + 2048;

    { // stage xk (swizzled) + eta
      int r = tid>>3, c0 = (tid&7)*8;
      bf8 vv = *(const bf8*)(xk + (size_t)r*3200 + c0);
      *(bf8*)&sXk[IDX(r, c0, 64)] = vv;
      if (tid < 64) Et[tid] = etb[c*64 + tid];
    }
    u16 tgp[2][4];
    #pragma unroll
    for (int n=0;n<2;++n)
      #pragma unroll
      for (int r=0;r<4;++r)
        tgp[n][r] = tg[(size_t)(mtw*16+lg*4+r)*3200 + (nw*2+n)*16+lr];
    __syncthreads();
    SB();

    // ---- S1: Z1 = xk@W1 + b1 ; X2 = gelu(Z1) -> sX2
    {
      f4 acc1[8];
      #pragma unroll
      for (int t=0;t<8;++t) acc1[t] = ZV;
      #pragma unroll
      for (int kc=0; kc<2; ++kc){
        bf8 a = *(const bf8*)&sXk[IDX(mtw*16+lr, kc*32+lg*8, 64)];
        #pragma unroll
        for (int t=0;t<8;++t){
          bf8 bb = *(const bf8*)&tW1[IDX((nw*8+t)*16+lr, kc*32+lg*8, 64)];
          acc1[t] = MFMA16(a, bb, acc1[t]);
        }
      }
      SB();
      #pragma unroll
      for (int t=0;t<8;++t){
        int col = (nw*8+t)*16 + lr;
        float bias = b1f[col];
        #pragma unroll
        for (int r=0;r<4;++r)
          sX2[IDX(mtw*16+lg*4+r, col, 256)] = f2bf(gelu_f(acc1[t][r] + bias));
      }
    }
    __syncthreads();
    SB();

    // ---- S2: Z2 = X2@W2 + b2
    f4 acc2[2];
    acc2[0] = ZV; acc2[1] = ZV;
    #pragma unroll
    for (int kc=0; kc<8; ++kc){
      bf8 a = *(const bf8*)&sX2[IDX(mtw*16+lr, kc*32+lg*8, 256)];
      #pragma unroll
      for (int n=0;n<2;++n){
        bf8 bb = *(const bf8*)&tW2[IDX((nw*2+n)*16+lr, kc*32+lg*8, 256)];
        acc2[n] = MFMA16(a, bb, acc2[n]);
      }
    }
    SB();
    {
      float ps[4], pq[4];
      #pragma unroll
      for (int r=0;r<4;++r){ ps[r]=0.f; pq[r]=0.f; }
      #pragma unroll
      for (int n=0;n<2;++n){
        float bias0 = b2f[(nw*2+n)*16+lr];
        #pragma unroll
        for (int r=0;r<4;++r){
          acc2[n][r] += bias0;
          ps[r] += acc2[n][r];
          pq[r] += acc2[n][r]*acc2[n][r];
        }
      }
      #pragma unroll
      for (int r=0;r<4;++r)
        #pragma unroll
        for (int off=1; off<16; off<<=1){ ps[r] += __shfl_xor(ps[r], off); pq[r] += __shfl_xor(pq[r], off); }
      if (lr == 0){
        #pragma unroll
        for (int r=0;r<4;++r){ st1[mtw*16+lg*4+r][nw*2] = ps[r]; st1[mtw*16+lg*4+r][nw*2+1] = pq[r]; }
      }
    }
    __syncthreads();
    SB();
    float gy[2][4], xh[2][4];
    {
      float pg[4], ph[4];
      #pragma unroll
      for (int r=0;r<4;++r){ pg[r]=0.f; ph[r]=0.f; }
      #pragma unroll
      for (int n=0;n<2;++n){
        int col = (nw*2+n)*16+lr;
        float g = gwv[col], bb = gbv[col];
        #pragma unroll
        for (int r=0;r<4;++r){
          int row = mtw*16+lg*4+r;
          float s1 = st1[row][0] + st1[row][2];
          float s2 = st1[row][1] + st1[row][3];
          float muv = s1 * (1.f/64.f);
          float rsv = rsqrtf(s2*(1.f/64.f) - muv*muv + 1e-6f);
          float x = (acc2[n][r] - muv) * rsv;
          float t = bf2f(tgp[n][r]);
          float gyv = (g*x + bb - t) * g;
          gy[n][r] = gyv; xh[n][r] = x;
          pg[r] += gyv; ph[r] += gyv*x;
        }
      }
      #pragma unroll
      for (int r=0;r<4;++r)
        #pragma unroll
        for (int off=1; off<16; off<<=1){ pg[r] += __shfl_xor(pg[r], off); ph[r] += __shfl_xor(ph[r], off); }
      if (lr == 0){
        #pragma unroll
        for (int r=0;r<4;++r){ st2[mtw*16+lg*4+r][nw*2] = pg[r]; st2[mtw*16+lg*4+r][nw*2+1] = ph[r]; }
      }
    }
    __syncthreads();
    SB();
    #pragma unroll
    for (int n=0;n<2;++n){
      int col = (nw*2+n)*16+lr;
      sh4 pk;
      #pragma unroll
      for (int r=0;r<4;++r){
        int row = mtw*16+lg*4+r;
        float s1 = st1[row][0] + st1[row][2];
        float s2 = st1[row][1] + st1[row][3];
        float muv = s1 * (1.f/64.f);
        float rsv = rsqrtf(s2*(1.f/64.f) - muv*muv + 1e-6f);   // bit-identical recompute
        float sg = st2[row][0] + st2[row][2];
        float sx = st2[row][1] + st2[row][3];
        float gz = (64.f*gy[n][r] - sg - xh[n][r]*sx) * (rsv * (1.f/64.f));
        pk[r] = (short)f2bf(gz);
      }
      *(sh4*)&tG2[IDX(col, mtw*16+lg*4, 64)] = pk;
    }
    __syncthreads();
    SB();

    // ---- S3: gZ1 = (gZ2 @ W2^T) * gelu_bwd(Z1); Z1 recomputed bit-identically
    bf8 aq0, aq1;
    {
      f4 acc3[8];
      #pragma unroll
      for (int t=0;t<8;++t) acc3[t] = ZV;
      #pragma unroll
      for (int kc=0; kc<2; ++kc){
        int k0 = kc*32 + lg*8;
        bf8 a;
        #pragma unroll
        for (int j=0;j<8;++j) a[j] = (short)tG2[IDX(k0+j, mtw*16+lr, 64)];
        #pragma unroll
        for (int t=0;t<8;++t){
          bf8 bb;
          #pragma unroll
          for (int j=0;j<8;++j) bb[j] = (short)tW2[IDX(k0+j, (nw*8+t)*16+lr, 256)];
          acc3[t] = MFMA16(a, bb, acc3[t]);
        }
      }
      SB();
      bf8 xk0 = *(const bf8*)&sXk[IDX(mtw*16+lr, 0*32+lg*8, 64)];
      bf8 xk1 = *(const bf8*)&sXk[IDX(mtw*16+lr, 1*32+lg*8, 64)];
      #pragma unroll
      for (int t=0;t<8;++t){
        int col = (nw*8+t)*16+lr;
        f4 z = ZV;
        z = MFMA16(xk0, *(const bf8*)&tW1[IDX(col, 0*32+lg*8, 64)], z);
        z = MFMA16(xk1, *(const bf8*)&tW1[IDX(col, 1*32+lg*8, 64)], z);
        float bias = b1f[col];
        sh4 pk;
        #pragma unroll
        for (int r=0;r<4;++r) pk[r] = (short)f2bf(acc3[t][r] * gelu_bwd_f(z[r] + bias));
        *(sh4*)&tG1[IDX(col, mtw*16+lg*4, 64)] = pk;
      }
      SB();
      // issue xq fragment loads late (first use: S4, next region)
      aq0 = *(const bf8*)(xq + (size_t)(mtw*16+lr)*3200 + lg*8);
      aq1 = *(const bf8*)(xq + (size_t)(mtw*16+lr)*3200 + 32 + lg*8);
    }
    __syncthreads();
    SB();

    // ---- S4: Attn1 -> M1
    {
      f4 accA[2];
      accA[0] = ZV; accA[1] = ZV;
      #pragma unroll
      for (int kc=0; kc<2; ++kc){
        bf8 a = kc ? aq1 : aq0;
        #pragma unroll
        for (int n=0;n<2;++n){
          bf8 bb = *(const bf8*)&sXk[IDX((nw*2+n)*16+lr, kc*32+lg*8, 64)];
          accA[n] = MFMA16(a, bb, accA[n]);
        }
      }
      SB();
      #pragma unroll
      for (int n=0;n<2;++n){
        int col = (nw*2+n)*16+lr;
        float e = Et[col];
        #pragma unroll
        for (int r=0;r<4;++r){
          int row = mtw*16+lg*4+r;
          float m = (col <= row) ? (-e * (accA[n][r] + 1.f)) : 0.f;
          sM[IDX(row, col, 64)] = f2bf(m);
        }
      }
    }
    __syncthreads();
    SB();

    // ---- S5: Z1_bar = xq@W1(old) + M1@gZ1 + b1 ; pack X2_bar bf16 immediately
    sh4 X2bp[8];
    {
      f4 acc4[8];
      #pragma unroll
      for (int t=0;t<8;++t) acc4[t] = ZV;
      #pragma unroll
      for (int kc=0; kc<2; ++kc){
        bf8 a = kc ? aq1 : aq0;
        #pragma unroll
        for (int t=0;t<8;++t){
          bf8 bb = *(const bf8*)&tW1[IDX((nw*8+t)*16+lr, kc*32+lg*8, 64)];
          acc4[t] = MFMA16(a, bb, acc4[t]);
        }
      }
      #pragma unroll
      for (int kc=0; kc<2; ++kc){
        bf8 a = *(const bf8*)&sM[IDX(mtw*16+lr, kc*32+lg*8, 64)];
        #pragma unroll
        for (int t=0;t<8;++t){
          bf8 bb = *(const bf8*)&tG1[IDX((nw*8+t)*16+lr, kc*32+lg*8, 64)];
          acc4[t] = MFMA16(a, bb, acc4[t]);
        }
      }
      SB();
      #pragma unroll
      for (int t=0;t<8;++t){
        float bias = b1f[(nw*8+t)*16+lr];
        #pragma unroll
        for (int r=0;r<4;++r) X2bp[t][r] = (short)f2bf(gelu_f(acc4[t][r] + bias));
      }
    }
    SB();
    // ---- S6': W1n = tW1(old) + (-eta*xk)^T @ gZ1 ; b1 colsum via Et-broadcast MFMA
    f4 W1n[8]; float b1d[8];
    #pragma unroll
    for (int t=0;t<8;++t){
      sh4 cf = *(const sh4*)&tW1[IDX((nw*8+t)*16+lr, mtw*16+lg*4, 64)];
      #pragma unroll
      for (int r=0;r<4;++r) W1n[t][r] = bf2f((u16)cf[r]);
    }
    SB();
    #pragma unroll
    for (int kc=0; kc<2; ++kc){
      int k0 = kc*32 + lg*8;
      bf8 xa, ea;
      #pragma unroll
      for (int j=0;j<8;++j){
        float e = Et[k0+j];
        ea[j] = (short)f2bf(e);
        xa[j] = (short)f2bf(-bf2f(sXk[IDX(k0+j, mtw*16+lr, 64)]) * e);
      }
      #pragma unroll
      for (int t=0;t<8;++t){
        bf8 bb = *(const bf8*)&tG1[IDX((nw*8+t)*16+lr, kc*32+lg*8, 64)];
        W1n[t] = MFMA16(xa, bb, W1n[t]);
        f4 d0 = ZV;
        d0 = MFMA16(ea, bb, d0);
        if (kc==0) b1d[t] = d0[0]; else b1d[t] += d0[0];
      }
    }
    __syncthreads();
    SB();
    // commit new W1 (bf16), write X2_bar over tG1, apply b1 delta
    u16* X2b = tG1;
    #pragma unroll
    for (int t=0;t<8;++t){
      int col = (nw*8+t)*16+lr;
      sh4 p1;
      #pragma unroll
      for (int r=0;r<4;++r){
        X2b[IDX(mtw*16+lg*4+r, col, 256)] = (u16)X2bp[t][r];
        p1[r] = (short)f2bf(W1n[t][r]);
      }
      *(sh4*)&tW1[IDX(col, mtw*16+lg*4, 64)] = p1;
    }
    if (mtw == 0 && lg == 0){
      #pragma unroll
      for (int t=0;t<8;++t) b1f[(nw*8+t)*16+lr] -= b1d[t];
    }
    __syncthreads();
    SB();

    // ---- S7: Attn2 -> M2
    {
      f4 accB[2];
      accB[0] = ZV; accB[1] = ZV;
      #pragma unroll
      for (int kc=0; kc<8; ++kc){
        bf8 a = *(const bf8*)&X2b[IDX(mtw*16+lr, kc*32+lg*8, 256)];
        #pragma unroll
        for (int n=0;n<2;++n){
          bf8 bb = *(const bf8*)&sX2[IDX((nw*2+n)*16+lr, kc*32+lg*8, 256)];
          accB[n] = MFMA16(a, bb, accB[n]);
        }
      }
      SB();
      #pragma unroll
      for (int n=0;n<2;++n){
        int col = (nw*2+n)*16+lr;
        float e = Et[col];
        #pragma unroll
        for (int r=0;r<4;++r){
          int row = mtw*16+lg*4+r;
          float m = (col <= row) ? (-e * (accB[n][r] + 1.f)) : 0.f;
          sM[IDX(row, col, 64)] = f2bf(m);
        }
      }
    }
    __syncthreads();
    SB();

    // ---- S8: Z2_bar = X2_bar@W2 + M2@gZ2 + b2 (acc6)
    f4 acc6[2];
    acc6[0] = ZV; acc6[1] = ZV;
    #pragma unroll
    for (int kc=0; kc<8; ++kc){
      bf8 a = *(const bf8*)&X2b[IDX(mtw*16+lr, kc*32+lg*8, 256)];
      #pragma unroll
      for (int n=0;n<2;++n){
        bf8 bb = *(const bf8*)&tW2[IDX((nw*2+n)*16+lr, kc*32+lg*8, 256)];
        acc6[n] = MFMA16(a, bb, acc6[n]);
      }
    }
    #pragma unroll
    for (int kc=0; kc<2; ++kc){
      bf8 a = *(const bf8*)&sM[IDX(mtw*16+lr, kc*32+lg*8, 64)];
      #pragma unroll
      for (int n=0;n<2;++n){
        bf8 bb = *(const bf8*)&tG2[IDX((nw*2+n)*16+lr, kc*32+lg*8, 64)];
        acc6[n] = MFMA16(a, bb, acc6[n]);
      }
    }
    SB();
    #pragma unroll
    for (int n=0;n<2;++n){
      float bias0 = b2f[(nw*2+n)*16+lr];
      #pragma unroll
      for (int r=0;r<4;++r) acc6[n][r] += bias0;
    }
    SB();
    // ---- S9': W2n = tW2(old) + (-eta*X2)^T @ gZ2 ; b2 colsum via Et-broadcast MFMA
    f4 W2n[8]; float b2d[2];
    #pragma unroll
    for (int t=0;t<8;++t){
      sh4 cf = *(const sh4*)&tW2[IDX((t>>1)*16+lr, (2*wid+(t&1))*16+lg*4, 256)];
      #pragma unroll
      for (int r=0;r<4;++r) W2n[t][r] = bf2f((u16)cf[r]);
    }
    SB();
    #pragma unroll
    for (int n=0;n<2;++n){
      f4 d = ZV;
      #pragma unroll
      for (int kc=0; kc<2; ++kc){
        int k0 = kc*32+lg*8;
        bf8 ea;
        #pragma unroll
        for (int j=0;j<8;++j) ea[j] = (short)f2bf(Et[k0+j]);
        bf8 bb = *(const bf8*)&tG2[IDX((nw*2+n)*16+lr, kc*32+lg*8, 64)];
        d = MFMA16(ea, bb, d);
      }
      b2d[n] = d[0];
    }
    SB();
    #pragma unroll
    for (int kc=0; kc<2; ++kc){
      int k0 = kc*32 + lg*8;
      bf8 a2[2];
      #pragma unroll
      for (int ta=0; ta<2; ++ta)
        #pragma unroll
        for (int j=0;j<8;++j) a2[ta][j] = (short)f2bf(-bf2f(sX2[IDX(k0+j, (2*wid+ta)*16+lr, 256)]) * Et[k0+j]);
      #pragma unroll
      for (int nb=0; nb<4; ++nb){
        bf8 bb = *(const bf8*)&tG2[IDX(nb*16+lr, kc*32+lg*8, 64)];
        #pragma unroll
        for (int ta=0; ta<2; ++ta) W2n[nb*2+ta] = MFMA16(a2[ta], bb, W2n[nb*2+ta]);
      }
    }
    __syncthreads();
    SB();
    // commit new W2, apply b2 delta, LN-fwd stats of Z2_bar
    #pragma unroll
    for (int t=0;t<8;++t){
      sh4 p2;
      #pragma unroll
      for (int r=0;r<4;++r) p2[r] = (short)f2bf(W2n[t][r]);
      *(sh4*)&tW2[IDX((t>>1)*16+lr, (2*wid+(t&1))*16+lg*4, 256)] = p2;
    }
    if (mtw == 0 && lg == 0){
      #pragma unroll
      for (int n=0;n<2;++n) b2f[(nw*2+n)*16+lr] -= b2d[n];
    }
    SB();
    {
      float ps[4], pq[4];
      #pragma unroll
      for (int r=0;r<4;++r){ ps[r]=0.f; pq[r]=0.f; }
      #pragma unroll
      for (int n=0;n<2;++n)
        #pragma unroll
        for (int r=0;r<4;++r){ ps[r] += acc6[n][r]; pq[r] += acc6[n][r]*acc6[n][r]; }
      #pragma unroll
      for (int r=0;r<4;++r)
        #pragma unroll
        for (int off=1; off<16; off<<=1){ ps[r] += __shfl_xor(ps[r], off); pq[r] += __shfl_xor(pq[r], off); }
      if (lr == 0){
        #pragma unroll
        for (int r=0;r<4;++r){ st1[mtw*16+lg*4+r][nw*2] = ps[r]; st1[mtw*16+lg*4+r][nw*2+1] = pq[r]; }
      }
    }
    __syncthreads();
    SB();
    // ---- S10: out = xq + ln_fwd(Z2_bar) (in place over target cols)
    #pragma unroll
    for (int r=0;r<4;++r){
      int row = mtw*16+lg*4+r;
      float s1 = st1[row][0] + st1[row][2];
      float s2 = st1[row][1] + st1[row][3];
      float m = s1 * (1.f/64.f);
      float rstd = rsqrtf(s2*(1.f/64.f) - m*m + 1e-6f);
      size_t ro = (size_t)row*3200;
      #pragma unroll
      for (int n=0;n<2;++n){
        int col = (nw*2+n)*16+lr;
        float val = bf2f(xq[ro+col]) + gwv[col]*(acc6[n][r]-m)*rstd + gbv[col];
        yrow[ro+col] = f2bf(val);
      }
    }
    __syncthreads();
  }
}

// ---------------------------------------------------------------- post layernorm over D=1024 (in place)
__global__ __launch_bounds__(256) void postln_kernel(u16* __restrict__ qkvl,
    const float* __restrict__ pw, const float* __restrict__ pb)
{
  int row = blockIdx.x;
  u16* rp = qkvl + (size_t)row*3200;
  float v[4]; float s1=0.f, s2=0.f;
  #pragma unroll
  for (int i=0;i<4;++i){ v[i] = bf2f(rp[2048 + threadIdx.x + i*256]); s1 += v[i]; s2 += v[i]*v[i]; }
  #pragma unroll
  for (int off=1; off<64; off<<=1){ s1 += __shfl_xor(s1, off); s2 += __shfl_xor(s2, off); }
  __shared__ float r1[4], r2[4];
  int w = threadIdx.x >> 6;
  if ((threadIdx.x & 63) == 0){ r1[w] = s1; r2[w] = s2; }
  __syncthreads();
  s1 = r1[0]+r1[1]+r1[2]+r1[3];
  s2 = r2[0]+r2[1]+r2[2]+r2[3];
  float mu = s1*(1.f/1024.f);
  float rstd = rsqrtf(s2*(1.f/1024.f) - mu*mu + 1e-6f);
  #pragma unroll
  for (int i=0;i<4;++i){
    int col = threadIdx.x + i*256;
    rp[col] = f2bf(pw[col]*(v[i]-mu)*rstd + pb[col]);
  }
}

// ---------------------------------------------------------------- launch
extern "C" void kernel_launch(void* const* d_in, const int* in_sizes, int n_in,
                              void* d_out, int out_size, void* d_ws, size_t ws_size,
                              hipStream_t stream)
{
  const float* x   = (const float*)d_in[0];
  const float* Wq  = (const float*)d_in[1];
  const float* Wk  = (const float*)d_in[2];
  const float* Wv  = (const float*)d_in[3];
  const float* Wo  = (const float*)d_in[4];
  const float* W1  = (const float*)d_in[5];
  const float* b1  = (const float*)d_in[6];
  const float* W2  = (const float*)d_in[7];
  const float* b2  = (const float*)d_in[8];
  const float* tnw = (const float*)d_in[9];
  const float* tnb = (const float*)d_in[10];
  const float* lrw = (const float*)d_in[11];
  const float* lrb = (const float*)d_in[12];
  const float* pnw = (const float*)d_in[13];
  const float* pnb = (const float*)d_in[14];
  (void)in_sizes; (void)n_in; (void)out_size; (void)ws_size;

  u16* qkvl  = (u16*)d_ws;                       // [8192][3200] bf16 = 50 MB
  u16* wcat  = (u16*)d_out;                      // d_out scratch; dead before final GEMM
  float* etg = (float*)((char*)d_out + 6553600);

  convert_kernel<<<1024, 256, 0, stream>>>(Wq, Wk, Wv, lrw, wcat);
  gemm_kernel<1,0,0><<<dim3(25, 64), 256, 0, stream>>>(x, wcat, qkvl, 8192, 3200, 1024, 1024, 1024, 3200);
  postproc_kernel<<<8192, 1024, 0, stream>>>(qkvl, tnw, tnb, lrb, etg);
  scan_kernel<<<64, 512, 0, stream>>>(qkvl, etg, W1, b1, W2, b2, tnw, tnb);
  postln_kernel<<<8192, 256, 0, stream>>>(qkvl, pnw, pnb);
  gemm_kernel<0,1,1><<<dim3(8, 64), 256, 0, stream>>>(qkvl, Wo, d_out, 8192, 1024, 1024, 3200, 1024, 1024);
}

// Round 17
// 1027.128 us; speedup vs baseline: 1.5691x; 1.0680x over previous
//
#include <hip/hip_runtime.h>

typedef unsigned short u16;
typedef __attribute__((ext_vector_type(8))) short bf8;
typedef __attribute__((ext_vector_type(4))) short sh4;
typedef __attribute__((ext_vector_type(4))) float f4;

#define MFMA16(a,b,c) __builtin_amdgcn_mfma_f32_16x16x32_bf16((a),(b),(c),0,0,0)
#define SB() __builtin_amdgcn_sched_barrier(0)

__device__ __forceinline__ float bf2f(u16 u){ return __uint_as_float(((unsigned)u)<<16); }
__device__ __forceinline__ u16 f2bf(float f){
  unsigned u = __float_as_uint(f);
  u += 0x7fffu + ((u>>16)&1u);
  return (u16)(u>>16);
}
__device__ __forceinline__ float tanh_fast(float x){
  x = fminf(fmaxf(x, -15.f), 15.f);
  float e = __expf(2.f*x);
  return (e-1.f)/(e+1.f);
}
#define GELU_C 0.7978845608028654f
__device__ __forceinline__ float gelu_f(float x){
  float t = tanh_fast(GELU_C*(x + 0.044715f*x*x*x));
  return 0.5f*x*(1.f+t);
}
__device__ __forceinline__ float gelu_bwd_f(float x){
  float t = tanh_fast(GELU_C*(x + 0.044715f*x*x*x));
  return 0.5f*(1.f+t) + 0.5f*x*(1.f-t*t)*GELU_C*(1.f+0.134145f*x*x);
}

// Scan-kernel LDS swizzle: f = r&7 only. Row steps of 16 (the unrolled t index)
// leave the swizzle invariant -> LDS addresses are affine in t -> compiler folds
// them into ds_read/ds_write offset immediates (address-VALU collapse vs the
// old (r>>3)^r form). r/r+8 2-way bank alias is free (m136).
__device__ __forceinline__ int IDX(int r, int c, int ldc){
  int f = r & 7;
  return r*ldc + ((((c>>3) ^ f)<<3) | (c&7));
}

// ---------------------------------------------------------------- convert: build wcat in d_out scratch
__global__ void convert_kernel(const float* __restrict__ Wq, const float* __restrict__ Wk,
    const float* __restrict__ Wv, const float* __restrict__ lrw, u16* __restrict__ wcat)
{
  size_t i0 = (size_t)blockIdx.x*blockDim.x + threadIdx.x;
  size_t stride = (size_t)gridDim.x*blockDim.x;
  for (size_t i=i0; i<3276800u; i+=stride){
    int n = (int)(i>>10);
    float v;
    if (n < 1024) v = Wq[i];
    else if (n < 2048) v = Wk[i - 1048576u];
    else if (n < 3072) v = Wv[i - 2097152u];
    else if (n < 3088) v = lrw[i - 3145728u];
    else v = 0.f;
    wcat[i] = f2bf(v);
  }
}

// ---------------------------------------------------------------- GEMM  C[M,N] = A[M,K] @ B[N,K]^T
template<int AF32, int BF32, int COUT>
__global__ __launch_bounds__(256) void gemm_kernel(const void* __restrict__ Ap, const void* __restrict__ Bp,
    void* __restrict__ C, int M, int N, int K, int lda, int ldb, int ldc)
{
  __shared__ __align__(16) u16 sA[128*64];
  __shared__ __align__(16) u16 sB[128*64];
  const int tid = threadIdx.x;
  const int lane = tid & 63, wid = tid >> 6;
  const int lr = lane & 15, lg = lane >> 4;
  const int wm = wid >> 1, wn = wid & 1;
  const int m0 = blockIdx.y*128, n0 = blockIdx.x*128;
  f4 acc[4][4];
  #pragma unroll
  for (int mi=0;mi<4;++mi)
    #pragma unroll
    for (int ni=0;ni<4;++ni){ acc[mi][ni][0]=0.f; acc[mi][ni][1]=0.f; acc[mi][ni][2]=0.f; acc[mi][ni][3]=0.f; }
  for (int k0=0; k0<K; k0+=64){
    #pragma unroll
    for (int i=0;i<4;++i){
      int cid = i*256 + tid;
      int row = cid>>3, cc = cid&7;
      int sl = cc ^ (row&7);
      bf8 pa, pb;
      if (AF32){
        const float* p = (const float*)Ap + (size_t)(m0+row)*lda + k0 + cc*8;
        #pragma unroll
        for (int j=0;j<8;++j) pa[j] = (short)f2bf(p[j]);
      } else {
        pa = *(const bf8*)((const u16*)Ap + (size_t)(m0+row)*lda + k0 + cc*8);
      }
      if (BF32){
        const float* p = (const float*)Bp + (size_t)(n0+row)*ldb + k0 + cc*8;
        #pragma unroll
        for (int j=0;j<8;++j) pb[j] = (short)f2bf(p[j]);
      } else {
        pb = *(const bf8*)((const u16*)Bp + (size_t)(n0+row)*ldb + k0 + cc*8);
      }
      *(bf8*)&sA[row*64 + sl*8] = pa;
      *(bf8*)&sB[row*64 + sl*8] = pb;
    }
    __syncthreads();
    #pragma unroll
    for (int kc=0;kc<2;++kc){
      bf8 av[4], bv[4];
      #pragma unroll
      for (int i=0;i<4;++i){
        int ra = wm*64 + i*16 + lr;
        av[i] = *(const bf8*)&sA[ra*64 + ((kc*4+lg)^(ra&7))*8];
        int rb = wn*64 + i*16 + lr;
        bv[i] = *(const bf8*)&sB[rb*64 + ((kc*4+lg)^(rb&7))*8];
      }
      #pragma unroll
      for (int mi=0;mi<4;++mi)
        #pragma unroll
        for (int ni=0;ni<4;++ni)
          acc[mi][ni] = MFMA16(av[mi], bv[ni], acc[mi][ni]);
    }
    __syncthreads();
  }
  #pragma unroll
  for (int mi=0;mi<4;++mi)
    #pragma unroll
    for (int ni=0;ni<4;++ni)
      #pragma unroll
      for (int r=0;r<4;++r){
        int row = m0 + wm*64 + mi*16 + lg*4 + r;
        int col = n0 + wn*64 + ni*16 + lr;
        if (COUT) ((float*)C)[(size_t)row*ldc + col] = acc[mi][ni][r];
        else ((u16*)C)[(size_t)row*ldc + col] = f2bf(acc[mi][ni][r]);
      }
}

// ---------------------------------------------------------------- postprocess IN PLACE on qkvl rows
__global__ __launch_bounds__(1024) void postproc_kernel(
    u16* __restrict__ qkvl, const float* __restrict__ tnw, const float* __restrict__ tnb,
    const float* __restrict__ lrb, float* __restrict__ eto)
{
  int row = blockIdx.x;              // b*2048 + l
  int l = row & 2047;
  int h = threadIdx.x >> 6;
  int d = threadIdx.x & 63;
  u16* rp = qkvl + (size_t)row*3200;
  float q = bf2f(rp[h*64+d]);
  float k = bf2f(rp[1024 + h*64+d]);
  float v = bf2f(rp[2048 + h*64+d]);
  float nq = q*q, nk = k*k;
  #pragma unroll
  for (int off=1; off<64; off<<=1){ nq += __shfl_xor(nq, off); nk += __shfl_xor(nk, off); }
  q = q / fmaxf(sqrtf(nq), 1e-12f);
  k = k / fmaxf(sqrtf(nk), 1e-12f);
  int pos = l & 63;
  float invf = __expf((float)(d&31) * -0.2878231366f);   // ln(10000)/32
  float f = (float)pos * invf;
  float sn, cs; sincosf(f, &sn, &cs);
  float qp = __shfl_xor(q, 32), kp = __shfl_xor(k, 32);
  float qr = q*cs + ((d<32) ? -qp : qp)*sn;
  float kr = k*cs + ((d<32) ? -kp : kp)*sn;
  float dv = v - kr;
  float mu = dv;
  #pragma unroll
  for (int off=1; off<64; off<<=1) mu += __shfl_xor(mu, off);
  mu *= (1.f/64.f);
  float cdv = dv - mu;
  float s2 = cdv*cdv;
  #pragma unroll
  for (int off=1; off<64; off<<=1) s2 += __shfl_xor(s2, off);
  float sd = sqrtf(s2 * (1.f/63.f));
  float tgt = tnw[h*64+d]*cdv/(sd + 1e-8f) + tnb[h*64+d];
  float lgt = bf2f(rp[3072+h]) + lrb[h];
  rp[h*64+d]        = f2bf(qr);
  rp[1024 + h*64+d] = f2bf(kr);
  rp[2048 + h*64+d] = f2bf(tgt);
  if (d == 0)
    eto[(size_t)((row>>11)*16 + h)*2048 + l] = (1.f/(1.f+__expf(-lgt))) * (1.f/64.f);
}

// ---------------------------------------------------------------- TTT scan: one block per (b,h), 8 waves
// R11 base (512t / 128 VGPR, masters bf16 in LDS, anti-LICM opaque index copies).
// R17: t-affine swizzle (f=r&7) for LDS-offset-immediate folding; Attn1 fused into
// the S1 phase (one fewer barrier, MFMA overlap).
__global__ __launch_bounds__(512) void scan_kernel(
    u16* __restrict__ qkvl, const float* __restrict__ etg,
    const float* __restrict__ W1g, const float* __restrict__ b1g,
    const float* __restrict__ W2g, const float* __restrict__ b2g,
    const float* __restrict__ tnw, const float* __restrict__ tnb)
{
  __shared__ __align__(16) u16 tW1[16384];   // [256][64] W1^T swizzled, bf16 master
  __shared__ __align__(16) u16 tW2[16384];   // [64][256] W2^T swizzled, bf16 master
  __shared__ __align__(16) u16 sX2[16384];   // [64][256]
  __shared__ __align__(16) u16 tG1[16384];   // [256][64] gZ1^T; reused as X2bar [64][256]
  __shared__ __align__(16) u16 sXk[4096];    // [64][64]
  __shared__ __align__(16) u16 tG2[4096];    // [64][64] gZ2^T
  __shared__ __align__(16) u16 sM[4096];     // [64][64]
  __shared__ float b1f[256];
  __shared__ float b2f[64];
  __shared__ float Et[64];
  __shared__ float gwv[64], gbv[64];
  __shared__ float st1[64][4];
  __shared__ float st2[64][4];

  const int tid0 = threadIdx.x;
  const int lr0 = tid0 & 15;
  const int lg0 = (tid0 & 63) >> 4;
  const int wid0 = tid0 >> 6;   // 0..7
  const int mtw0 = wid0 >> 1;   // 0..3
  const int nw0  = wid0 & 1;    // 0..1
  const int bh = blockIdx.x;
  const int h = bh & 15;
  const int b = bh >> 4;
  const f4 ZV = {0.f, 0.f, 0.f, 0.f};

  if (tid0 < 64){ gwv[tid0] = tnw[h*64+tid0]; gbv[tid0] = tnb[h*64+tid0]; b2f[tid0] = b2g[h*64+tid0]; }
  if (tid0 < 256) b1f[tid0] = b1g[h*256+tid0];

  #pragma unroll
  for (int t=0;t<8;++t){
    sh4 p1, p2;
    #pragma unroll
    for (int r=0;r<4;++r){
      p1[r] = (short)f2bf(W1g[(size_t)h*16384 + (mtw0*16+lg0*4+r)*256 + (nw0*8+t)*16+lr0]);
      p2[r] = (short)f2bf(W2g[(size_t)h*16384 + ((2*wid0+(t&1))*16+lg0*4+r)*64 + (t>>1)*16+lr0]);
    }
    *(sh4*)&tW1[IDX((nw0*8+t)*16+lr0, mtw0*16+lg0*4, 64)] = p1;
    *(sh4*)&tW2[IDX((t>>1)*16+lr0, (2*wid0+(t&1))*16+lg0*4, 256)] = p2;
  }
  __syncthreads();

  u16* qb = qkvl + (size_t)(b*2048)*3200 + h*64;
  const float* etb = etg + (size_t)bh*2048;

  for (int c=0; c<32; ++c){
    // Anti-LICM: every derived LDS/global address is loop-variant -> recomputed
    // per chunk (cheap VALU) instead of hoisted+spilled (the R10 pathology).
    int tid = tid0, lr = lr0, lg = lg0, mtw = mtw0, nw = nw0, wid = wid0;
    asm volatile("" : "+v"(tid), "+v"(lr), "+v"(lg), "+v"(mtw), "+v"(nw), "+v"(wid));

    u16* xq = qb + (size_t)c*64*3200;
    const u16* xk = xq + 1024;
    const u16* tg = xq + 2048;
    u16* yrow = xq + 2048;

    { // stage xk (swizzled) + eta
      int r = tid>>3, c0 = (tid&7)*8;
      bf8 vv = *(const bf8*)(xk + (size_t)r*3200 + c0);
      *(bf8*)&sXk[IDX(r, c0, 64)] = vv;
      if (tid < 64) Et[tid] = etb[c*64 + tid];
    }
    // xq fragments + targets (global, L2-hot; used in the fused S1 phase and S5)
    bf8 aq0 = *(const bf8*)(xq + (size_t)(mtw*16+lr)*3200 + lg*8);
    bf8 aq1 = *(const bf8*)(xq + (size_t)(mtw*16+lr)*3200 + 32 + lg*8);
    u16 tgp[2][4];
    #pragma unroll
    for (int n=0;n<2;++n)
      #pragma unroll
      for (int r=0;r<4;++r)
        tgp[n][r] = tg[(size_t)(mtw*16+lg*4+r)*3200 + (nw*2+n)*16+lr];
    __syncthreads();
    SB();

    // ---- S1 (+fused Attn1): Z1 = xk@W1 + b1 ; X2 = gelu(Z1) -> sX2 ;
    //      Attn1 = tril(xq@xk^T) -> M1 -> sM (sM not read until S5)
    {
      f4 acc1[8];
      #pragma unroll
      for (int t=0;t<8;++t) acc1[t] = ZV;
      #pragma unroll
      for (int kc=0; kc<2; ++kc){
        bf8 a = *(const bf8*)&sXk[IDX(mtw*16+lr, kc*32+lg*8, 64)];
        #pragma unroll
        for (int t=0;t<8;++t){
          bf8 bb = *(const bf8*)&tW1[IDX((nw*8+t)*16+lr, kc*32+lg*8, 64)];
          acc1[t] = MFMA16(a, bb, acc1[t]);
        }
      }
      f4 accA[2];
      accA[0] = ZV; accA[1] = ZV;
      #pragma unroll
      for (int kc=0; kc<2; ++kc){
        bf8 a = kc ? aq1 : aq0;
        #pragma unroll
        for (int n=0;n<2;++n){
          bf8 bb = *(const bf8*)&sXk[IDX((nw*2+n)*16+lr, kc*32+lg*8, 64)];
          accA[n] = MFMA16(a, bb, accA[n]);
        }
      }
      SB();
      #pragma unroll
      for (int t=0;t<8;++t){
        int col = (nw*8+t)*16 + lr;
        float bias = b1f[col];
        #pragma unroll
        for (int r=0;r<4;++r)
          sX2[IDX(mtw*16+lg*4+r, col, 256)] = f2bf(gelu_f(acc1[t][r] + bias));
      }
      #pragma unroll
      for (int n=0;n<2;++n){
        int col = (nw*2+n)*16+lr;
        float e = Et[col];
        #pragma unroll
        for (int r=0;r<4;++r){
          int row = mtw*16+lg*4+r;
          float m = (col <= row) ? (-e * (accA[n][r] + 1.f)) : 0.f;
          sM[IDX(row, col, 64)] = f2bf(m);
        }
      }
    }
    __syncthreads();
    SB();

    // ---- S2: Z2 = X2@W2 + b2
    f4 acc2[2];
    acc2[0] = ZV; acc2[1] = ZV;
    #pragma unroll
    for (int kc=0; kc<8; ++kc){
      bf8 a = *(const bf8*)&sX2[IDX(mtw*16+lr, kc*32+lg*8, 256)];
      #pragma unroll
      for (int n=0;n<2;++n){
        bf8 bb = *(const bf8*)&tW2[IDX((nw*2+n)*16+lr, kc*32+lg*8, 256)];
        acc2[n] = MFMA16(a, bb, acc2[n]);
      }
    }
    SB();
    {
      float ps[4], pq[4];
      #pragma unroll
      for (int r=0;r<4;++r){ ps[r]=0.f; pq[r]=0.f; }
      #pragma unroll
      for (int n=0;n<2;++n){
        float bias0 = b2f[(nw*2+n)*16+lr];
        #pragma unroll
        for (int r=0;r<4;++r){
          acc2[n][r] += bias0;
          ps[r] += acc2[n][r];
          pq[r] += acc2[n][r]*acc2[n][r];
        }
      }
      #pragma unroll
      for (int r=0;r<4;++r)
        #pragma unroll
        for (int off=1; off<16; off<<=1){ ps[r] += __shfl_xor(ps[r], off); pq[r] += __shfl_xor(pq[r], off); }
      if (lr == 0){
        #pragma unroll
        for (int r=0;r<4;++r){ st1[mtw*16+lg*4+r][nw*2] = ps[r]; st1[mtw*16+lg*4+r][nw*2+1] = pq[r]; }
      }
    }
    __syncthreads();
    SB();
    float gy[2][4], xh[2][4];
    {
      float pg[4], ph[4];
      #pragma unroll
      for (int r=0;r<4;++r){ pg[r]=0.f; ph[r]=0.f; }
      #pragma unroll
      for (int n=0;n<2;++n){
        int col = (nw*2+n)*16+lr;
        float g = gwv[col], bb = gbv[col];
        #pragma unroll
        for (int r=0;r<4;++r){
          int row = mtw*16+lg*4+r;
          float s1 = st1[row][0] + st1[row][2];
          float s2 = st1[row][1] + st1[row][3];
          float muv = s1 * (1.f/64.f);
          float rsv = rsqrtf(s2*(1.f/64.f) - muv*muv + 1e-6f);
          float x = (acc2[n][r] - muv) * rsv;
          float t = bf2f(tgp[n][r]);
          float gyv = (g*x + bb - t) * g;
          gy[n][r] = gyv; xh[n][r] = x;
          pg[r] += gyv; ph[r] += gyv*x;
        }
      }
      #pragma unroll
      for (int r=0;r<4;++r)
        #pragma unroll
        for (int off=1; off<16; off<<=1){ pg[r] += __shfl_xor(pg[r], off); ph[r] += __shfl_xor(ph[r], off); }
      if (lr == 0){
        #pragma unroll
        for (int r=0;r<4;++r){ st2[mtw*16+lg*4+r][nw*2] = pg[r]; st2[mtw*16+lg*4+r][nw*2+1] = ph[r]; }
      }
    }
    __syncthreads();
    SB();
    #pragma unroll
    for (int n=0;n<2;++n){
      int col = (nw*2+n)*16+lr;
      sh4 pk;
      #pragma unroll
      for (int r=0;r<4;++r){
        int row = mtw*16+lg*4+r;
        float s1 = st1[row][0] + st1[row][2];
        float s2 = st1[row][1] + st1[row][3];
        float muv = s1 * (1.f/64.f);
        float rsv = rsqrtf(s2*(1.f/64.f) - muv*muv + 1e-6f);   // bit-identical recompute
        float sg = st2[row][0] + st2[row][2];
        float sx = st2[row][1] + st2[row][3];
        float gz = (64.f*gy[n][r] - sg - xh[n][r]*sx) * (rsv * (1.f/64.f));
        pk[r] = (short)f2bf(gz);
      }
      *(sh4*)&tG2[IDX(col, mtw*16+lg*4, 64)] = pk;
    }
    __syncthreads();
    SB();

    // ---- S3: gZ1 = (gZ2 @ W2^T) * gelu_bwd(Z1); Z1 recomputed bit-identically
    {
      f4 acc3[8];
      #pragma unroll
      for (int t=0;t<8;++t) acc3[t] = ZV;
      #pragma unroll
      for (int kc=0; kc<2; ++kc){
        int k0 = kc*32 + lg*8;
        bf8 a;
        #pragma unroll
        for (int j=0;j<8;++j) a[j] = (short)tG2[IDX(k0+j, mtw*16+lr, 64)];
        #pragma unroll
        for (int t=0;t<8;++t){
          bf8 bb;
          #pragma unroll
          for (int j=0;j<8;++j) bb[j] = (short)tW2[IDX(k0+j, (nw*8+t)*16+lr, 256)];
          acc3[t] = MFMA16(a, bb, acc3[t]);
        }
      }
      SB();
      bf8 xk0 = *(const bf8*)&sXk[IDX(mtw*16+lr, 0*32+lg*8, 64)];
      bf8 xk1 = *(const bf8*)&sXk[IDX(mtw*16+lr, 1*32+lg*8, 64)];
      #pragma unroll
      for (int t=0;t<8;++t){
        int col = (nw*8+t)*16+lr;
        f4 z = ZV;
        z = MFMA16(xk0, *(const bf8*)&tW1[IDX(col, 0*32+lg*8, 64)], z);
        z = MFMA16(xk1, *(const bf8*)&tW1[IDX(col, 1*32+lg*8, 64)], z);
        float bias = b1f[col];
        sh4 pk;
        #pragma unroll
        for (int r=0;r<4;++r) pk[r] = (short)f2bf(acc3[t][r] * gelu_bwd_f(z[r] + bias));
        *(sh4*)&tG1[IDX(col, mtw*16+lg*4, 64)] = pk;
      }
    }
    __syncthreads();
    SB();

    // ---- S5: Z1_bar = xq@W1(old) + M1@gZ1 + b1 ; pack X2_bar bf16 immediately
    sh4 X2bp[8];
    {
      f4 acc4[8];
      #pragma unroll
      for (int t=0;t<8;++t) acc4[t] = ZV;
      #pragma unroll
      for (int kc=0; kc<2; ++kc){
        bf8 a = kc ? aq1 : aq0;
        #pragma unroll
        for (int t=0;t<8;++t){
          bf8 bb = *(const bf8*)&tW1[IDX((nw*8+t)*16+lr, kc*32+lg*8, 64)];
          acc4[t] = MFMA16(a, bb, acc4[t]);
        }
      }
      #pragma unroll
      for (int kc=0; kc<2; ++kc){
        bf8 a = *(const bf8*)&sM[IDX(mtw*16+lr, kc*32+lg*8, 64)];
        #pragma unroll
        for (int t=0;t<8;++t){
          bf8 bb = *(const bf8*)&tG1[IDX((nw*8+t)*16+lr, kc*32+lg*8, 64)];
          acc4[t] = MFMA16(a, bb, acc4[t]);
        }
      }
      SB();
      #pragma unroll
      for (int t=0;t<8;++t){
        float bias = b1f[(nw*8+t)*16+lr];
        #pragma unroll
        for (int r=0;r<4;++r) X2bp[t][r] = (short)f2bf(gelu_f(acc4[t][r] + bias));
      }
    }
    SB();
    // ---- S6': W1n = tW1(old) + (-eta*xk)^T @ gZ1 ; b1 colsum via Et-broadcast MFMA
    f4 W1n[8]; float b1d[8];
    #pragma unroll
    for (int t=0;t<8;++t){
      sh4 cf = *(const sh4*)&tW1[IDX((nw*8+t)*16+lr, mtw*16+lg*4, 64)];
      #pragma unroll
      for (int r=0;r<4;++r) W1n[t][r] = bf2f((u16)cf[r]);
    }
    SB();
    #pragma unroll
    for (int kc=0; kc<2; ++kc){
      int k0 = kc*32 + lg*8;
      bf8 xa, ea;
      #pragma unroll
      for (int j=0;j<8;++j){
        float e = Et[k0+j];
        ea[j] = (short)f2bf(e);
        xa[j] = (short)f2bf(-bf2f(sXk[IDX(k0+j, mtw*16+lr, 64)]) * e);
      }
      #pragma unroll
      for (int t=0;t<8;++t){
        bf8 bb = *(const bf8*)&tG1[IDX((nw*8+t)*16+lr, kc*32+lg*8, 64)];
        W1n[t] = MFMA16(xa, bb, W1n[t]);
        f4 d0 = ZV;
        d0 = MFMA16(ea, bb, d0);
        if (kc==0) b1d[t] = d0[0]; else b1d[t] += d0[0];
      }
    }
    __syncthreads();
    SB();
    // commit new W1 (bf16), write X2_bar over tG1, apply b1 delta
    u16* X2b = tG1;
    #pragma unroll
    for (int t=0;t<8;++t){
      int col = (nw*8+t)*16+lr;
      sh4 p1;
      #pragma unroll
      for (int r=0;r<4;++r){
        X2b[IDX(mtw*16+lg*4+r, col, 256)] = (u16)X2bp[t][r];
        p1[r] = (short)f2bf(W1n[t][r]);
      }
      *(sh4*)&tW1[IDX(col, mtw*16+lg*4, 64)] = p1;
    }
    if (mtw == 0 && lg == 0){
      #pragma unroll
      for (int t=0;t<8;++t) b1f[(nw*8+t)*16+lr] -= b1d[t];
    }
    __syncthreads();
    SB();

    // ---- S7: Attn2 -> M2
    {
      f4 accB[2];
      accB[0] = ZV; accB[1] = ZV;
      #pragma unroll
      for (int kc=0; kc<8; ++kc){
        bf8 a = *(const bf8*)&X2b[IDX(mtw*16+lr, kc*32+lg*8, 256)];
        #pragma unroll
        for (int n=0;n<2;++n){
          bf8 bb = *(const bf8*)&sX2[IDX((nw*2+n)*16+lr, kc*32+lg*8, 256)];
          accB[n] = MFMA16(a, bb, accB[n]);
        }
      }
      SB();
      #pragma unroll
      for (int n=0;n<2;++n){
        int col = (nw*2+n)*16+lr;
        float e = Et[col];
        #pragma unroll
        for (int r=0;r<4;++r){
          int row = mtw*16+lg*4+r;
          float m = (col <= row) ? (-e * (accB[n][r] + 1.f)) : 0.f;
          sM[IDX(row, col, 64)] = f2bf(m);
        }
      }
    }
    __syncthreads();
    SB();

    // ---- S8: Z2_bar = X2_bar@W2 + M2@gZ2 + b2 (acc6)
    f4 acc6[2];
    acc6[0] = ZV; acc6[1] = ZV;
    #pragma unroll
    for (int kc=0; kc<8; ++kc){
      bf8 a = *(const bf8*)&X2b[IDX(mtw*16+lr, kc*32+lg*8, 256)];
      #pragma unroll
      for (int n=0;n<2;++n){
        bf8 bb = *(const bf8*)&tW2[IDX((nw*2+n)*16+lr, kc*32+lg*8, 256)];
        acc6[n] = MFMA16(a, bb, acc6[n]);
      }
    }
    #pragma unroll
    for (int kc=0; kc<2; ++kc){
      bf8 a = *(const bf8*)&sM[IDX(mtw*16+lr, kc*32+lg*8, 64)];
      #pragma unroll
      for (int n=0;n<2;++n){
        bf8 bb = *(const bf8*)&tG2[IDX((nw*2+n)*16+lr, kc*32+lg*8, 64)];
        acc6[n] = MFMA16(a, bb, acc6[n]);
      }
    }
    SB();
    #pragma unroll
    for (int n=0;n<2;++n){
      float bias0 = b2f[(nw*2+n)*16+lr];
      #pragma unroll
      for (int r=0;r<4;++r) acc6[n][r] += bias0;
    }
    SB();
    // ---- S9': W2n = tW2(old) + (-eta*X2)^T @ gZ2 ; b2 colsum via Et-broadcast MFMA
    f4 W2n[8]; float b2d[2];
    #pragma unroll
    for (int t=0;t<8;++t){
      sh4 cf = *(const sh4*)&tW2[IDX((t>>1)*16+lr, (2*wid+(t&1))*16+lg*4, 256)];
      #pragma unroll
      for (int r=0;r<4;++r) W2n[t][r] = bf2f((u16)cf[r]);
    }
    SB();
    #pragma unroll
    for (int n=0;n<2;++n){
      f4 d = ZV;
      #pragma unroll
      for (int kc=0; kc<2; ++kc){
        int k0 = kc*32+lg*8;
        bf8 ea;
        #pragma unroll
        for (int j=0;j<8;++j) ea[j] = (short)f2bf(Et[k0+j]);
        bf8 bb = *(const bf8*)&tG2[IDX((nw*2+n)*16+lr, kc*32+lg*8, 64)];
        d = MFMA16(ea, bb, d);
      }
      b2d[n] = d[0];
    }
    SB();
    #pragma unroll
    for (int kc=0; kc<2; ++kc){
      int k0 = kc*32 + lg*8;
      bf8 a2[2];
      #pragma unroll
      for (int ta=0; ta<2; ++ta)
        #pragma unroll
        for (int j=0;j<8;++j) a2[ta][j] = (short)f2bf(-bf2f(sX2[IDX(k0+j, (2*wid+ta)*16+lr, 256)]) * Et[k0+j]);
      #pragma unroll
      for (int nb=0; nb<4; ++nb){
        bf8 bb = *(const bf8*)&tG2[IDX(nb*16+lr, kc*32+lg*8, 64)];
        #pragma unroll
        for (int ta=0; ta<2; ++ta) W2n[nb*2+ta] = MFMA16(a2[ta], bb, W2n[nb*2+ta]);
      }
    }
    __syncthreads();
    SB();
    // commit new W2, apply b2 delta, LN-fwd stats of Z2_bar
    #pragma unroll
    for (int t=0;t<8;++t){
      sh4 p2;
      #pragma unroll
      for (int r=0;r<4;++r) p2[r] = (short)f2bf(W2n[t][r]);
      *(sh4*)&tW2[IDX((t>>1)*16+lr, (2*wid+(t&1))*16+lg*4, 256)] = p2;
    }
    if (mtw == 0 && lg == 0){
      #pragma unroll
      for (int n=0;n<2;++n) b2f[(nw*2+n)*16+lr] -= b2d[n];
    }
    SB();
    {
      float ps[4], pq[4];
      #pragma unroll
      for (int r=0;r<4;++r){ ps[r]=0.f; pq[r]=0.f; }
      #pragma unroll
      for (int n=0;n<2;++n)
        #pragma unroll
        for (int r=0;r<4;++r){ ps[r] += acc6[n][r]; pq[r] += acc6[n][r]*acc6[n][r]; }
      #pragma unroll
      for (int r=0;r<4;++r)
        #pragma unroll
        for (int off=1; off<16; off<<=1){ ps[r] += __shfl_xor(ps[r], off); pq[r] += __shfl_xor(pq[r], off); }
      if (lr == 0){
        #pragma unroll
        for (int r=0;r<4;++r){ st1[mtw*16+lg*4+r][nw*2] = ps[r]; st1[mtw*16+lg*4+r][nw*2+1] = pq[r]; }
      }
    }
    __syncthreads();
    SB();
    // ---- S10: out = xq + ln_fwd(Z2_bar) (in place over target cols)
    #pragma unroll
    for (int r=0;r<4;++r){
      int row = mtw*16+lg*4+r;
      float s1 = st1[row][0] + st1[row][2];
      float s2 = st1[row][1] + st1[row][3];
      float m = s1 * (1.f/64.f);
      float rstd = rsqrtf(s2*(1.f/64.f) - m*m + 1e-6f);
      size_t ro = (size_t)row*3200;
      #pragma unroll
      for (int n=0;n<2;++n){
        int col = (nw*2+n)*16+lr;
        float val = bf2f(xq[ro+col]) + gwv[col]*(acc6[n][r]-m)*rstd + gbv[col];
        yrow[ro+col] = f2bf(val);
      }
    }
    __syncthreads();
  }
}

// ---------------------------------------------------------------- post layernorm over D=1024 (in place)
__global__ __launch_bounds__(256) void postln_kernel(u16* __restrict__ qkvl,
    const float* __restrict__ pw, const float* __restrict__ pb)
{
  int row = blockIdx.x;
  u16* rp = qkvl + (size_t)row*3200;
  float v[4]; float s1=0.f, s2=0.f;
  #pragma unroll
  for (int i=0;i<4;++i){ v[i] = bf2f(rp[2048 + threadIdx.x + i*256]); s1 += v[i]; s2 += v[i]*v[i]; }
  #pragma unroll
  for (int off=1; off<64; off<<=1){ s1 += __shfl_xor(s1, off); s2 += __shfl_xor(s2, off); }
  __shared__ float r1[4], r2[4];
  int w = threadIdx.x >> 6;
  if ((threadIdx.x & 63) == 0){ r1[w] = s1; r2[w] = s2; }
  __syncthreads();
  s1 = r1[0]+r1[1]+r1[2]+r1[3];
  s2 = r2[0]+r2[1]+r2[2]+r2[3];
  float mu = s1*(1.f/1024.f);
  float rstd = rsqrtf(s2*(1.f/1024.f) - mu*mu + 1e-6f);
  #pragma unroll
  for (int i=0;i<4;++i){
    int col = threadIdx.x + i*256;
    rp[col] = f2bf(pw[col]*(v[i]-mu)*rstd + pb[col]);
  }
}

// ---------------------------------------------------------------- launch
extern "C" void kernel_launch(void* const* d_in, const int* in_sizes, int n_in,
                              void* d_out, int out_size, void* d_ws, size_t ws_size,
                              hipStream_t stream)
{
  const float* x   = (const float*)d_in[0];
  const float* Wq  = (const float*)d_in[1];
  const float* Wk  = (const float*)d_in[2];
  const float* Wv  = (const float*)d_in[3];
  const float* Wo  = (const float*)d_in[4];
  const float* W1  = (const float*)d_in[5];
  const float* b1  = (const float*)d_in[6];
  const float* W2  = (const float*)d_in[7];
  const float* b2  = (const float*)d_in[8];
  const float* tnw = (const float*)d_in[9];
  const float* tnb = (const float*)d_in[10];
  const float* lrw = (const float*)d_in[11];
  const float* lrb = (const float*)d_in[12];
  const float* pnw = (const float*)d_in[13];
  const float* pnb = (const float*)d_in[14];
  (void)in_sizes; (void)n_in; (void)out_size; (void)ws_size;

  u16* qkvl  = (u16*)d_ws;                       // [8192][3200] bf16 = 50 MB
  u16* wcat  = (u16*)d_out;                      // d_out scratch; dead before final GEMM
  float* etg = (float*)((char*)d_out + 6553600);

  convert_kernel<<<1024, 256, 0, stream>>>(Wq, Wk, Wv, lrw, wcat);
  gemm_kernel<1,0,0><<<dim3(25, 64), 256, 0, stream>>>(x, wcat, qkvl, 8192, 3200, 1024, 1024, 1024, 3200);
  postproc_kernel<<<8192, 1024, 0, stream>>>(qkvl, tnw, tnb, lrb, etg);
  scan_kernel<<<64, 512, 0, stream>>>(qkvl, etg, W1, b1, W2, b2, tnw, tnb);
  postln_kernel<<<8192, 256, 0, stream>>>(qkvl, pnw, pnb);
  gemm_kernel<0,1,1><<<dim3(8, 64), 256, 0, stream>>>(qkvl, Wo, d_out, 8192, 1024, 1024, 3200, 1024, 1024);
}

// Round 18
// 906.338 us; speedup vs baseline: 1.7782x; 1.1333x over previous
//
#include <hip/hip_runtime.h>

typedef unsigned short u16;
typedef __attribute__((ext_vector_type(8))) short bf8;
typedef __attribute__((ext_vector_type(4))) short sh4;
typedef __attribute__((ext_vector_type(4))) float f4;

#define MFMA16(a,b,c) __builtin_amdgcn_mfma_f32_16x16x32_bf16((a),(b),(c),0,0,0)
#define SB() __builtin_amdgcn_sched_barrier(0)

__device__ __forceinline__ float bf2f(u16 u){ return __uint_as_float(((unsigned)u)<<16); }
// HW RNE bf16 conversion: v_cvt_pk_bf16_f32 (1 VALU op vs 4-5 for the integer-RNE form).
__device__ __forceinline__ u16 f2bf(float f){
  unsigned r;
  asm("v_cvt_pk_bf16_f32 %0, %1, %1" : "=v"(r) : "v"(f));
  return (u16)r;
}
// tanh = 1 - 2/(e^{2x}+1): no clamp needed (e=inf -> t=1, e=0 -> t=-1), and the
// 1-op v_rcp_f32 replaces the ~10-op exact-rounded f32 division.
__device__ __forceinline__ float tanh_fast(float x){
  float e = __expf(2.f*x);
  return 1.f - 2.f*__builtin_amdgcn_rcpf(e + 1.f);
}
#define GELU_C 0.7978845608028654f
__device__ __forceinline__ float gelu_f(float x){
  float t = tanh_fast(GELU_C*(x + 0.044715f*x*x*x));
  return 0.5f*x*(1.f+t);
}
__device__ __forceinline__ float gelu_bwd_f(float x){
  float t = tanh_fast(GELU_C*(x + 0.044715f*x*x*x));
  return 0.5f*(1.f+t) + 0.5f*x*(1.f-t*t)*GELU_C*(1.f+0.134145f*x*x);
}

// Scan-kernel LDS swizzle: f = r&7 (t-affine; folds into ds offset immediates).
__device__ __forceinline__ int IDX(int r, int c, int ldc){
  int f = r & 7;
  return r*ldc + ((((c>>3) ^ f)<<3) | (c&7));
}

// ---------------------------------------------------------------- convert: build wcat in d_out scratch
__global__ void convert_kernel(const float* __restrict__ Wq, const float* __restrict__ Wk,
    const float* __restrict__ Wv, const float* __restrict__ lrw, u16* __restrict__ wcat)
{
  size_t i0 = (size_t)blockIdx.x*blockDim.x + threadIdx.x;
  size_t stride = (size_t)gridDim.x*blockDim.x;
  for (size_t i=i0; i<3276800u; i+=stride){
    int n = (int)(i>>10);
    float v;
    if (n < 1024) v = Wq[i];
    else if (n < 2048) v = Wk[i - 1048576u];
    else if (n < 3072) v = Wv[i - 2097152u];
    else if (n < 3088) v = lrw[i - 3145728u];
    else v = 0.f;
    wcat[i] = f2bf(v);
  }
}

// ---------------------------------------------------------------- GEMM  C[M,N] = A[M,K] @ B[N,K]^T
template<int AF32, int BF32, int COUT>
__global__ __launch_bounds__(256) void gemm_kernel(const void* __restrict__ Ap, const void* __restrict__ Bp,
    void* __restrict__ C, int M, int N, int K, int lda, int ldb, int ldc)
{
  __shared__ __align__(16) u16 sA[128*64];
  __shared__ __align__(16) u16 sB[128*64];
  const int tid = threadIdx.x;
  const int lane = tid & 63, wid = tid >> 6;
  const int lr = lane & 15, lg = lane >> 4;
  const int wm = wid >> 1, wn = wid & 1;
  const int m0 = blockIdx.y*128, n0 = blockIdx.x*128;
  f4 acc[4][4];
  #pragma unroll
  for (int mi=0;mi<4;++mi)
    #pragma unroll
    for (int ni=0;ni<4;++ni){ acc[mi][ni][0]=0.f; acc[mi][ni][1]=0.f; acc[mi][ni][2]=0.f; acc[mi][ni][3]=0.f; }
  for (int k0=0; k0<K; k0+=64){
    #pragma unroll
    for (int i=0;i<4;++i){
      int cid = i*256 + tid;
      int row = cid>>3, cc = cid&7;
      int sl = cc ^ (row&7);
      bf8 pa, pb;
      if (AF32){
        const float* p = (const float*)Ap + (size_t)(m0+row)*lda + k0 + cc*8;
        #pragma unroll
        for (int j=0;j<8;++j) pa[j] = (short)f2bf(p[j]);
      } else {
        pa = *(const bf8*)((const u16*)Ap + (size_t)(m0+row)*lda + k0 + cc*8);
      }
      if (BF32){
        const float* p = (const float*)Bp + (size_t)(n0+row)*ldb + k0 + cc*8;
        #pragma unroll
        for (int j=0;j<8;++j) pb[j] = (short)f2bf(p[j]);
      } else {
        pb = *(const bf8*)((const u16*)Bp + (size_t)(n0+row)*ldb + k0 + cc*8);
      }
      *(bf8*)&sA[row*64 + sl*8] = pa;
      *(bf8*)&sB[row*64 + sl*8] = pb;
    }
    __syncthreads();
    #pragma unroll
    for (int kc=0;kc<2;++kc){
      bf8 av[4], bv[4];
      #pragma unroll
      for (int i=0;i<4;++i){
        int ra = wm*64 + i*16 + lr;
        av[i] = *(const bf8*)&sA[ra*64 + ((kc*4+lg)^(ra&7))*8];
        int rb = wn*64 + i*16 + lr;
        bv[i] = *(const bf8*)&sB[rb*64 + ((kc*4+lg)^(rb&7))*8];
      }
      #pragma unroll
      for (int mi=0;mi<4;++mi)
        #pragma unroll
        for (int ni=0;ni<4;++ni)
          acc[mi][ni] = MFMA16(av[mi], bv[ni], acc[mi][ni]);
    }
    __syncthreads();
  }
  #pragma unroll
  for (int mi=0;mi<4;++mi)
    #pragma unroll
    for (int ni=0;ni<4;++ni)
      #pragma unroll
      for (int r=0;r<4;++r){
        int row = m0 + wm*64 + mi*16 + lg*4 + r;
        int col = n0 + wn*64 + ni*16 + lr;
        if (COUT) ((float*)C)[(size_t)row*ldc + col] = acc[mi][ni][r];
        else ((u16*)C)[(size_t)row*ldc + col] = f2bf(acc[mi][ni][r]);
      }
}

// ---------------------------------------------------------------- postprocess IN PLACE on qkvl rows
__global__ __launch_bounds__(1024) void postproc_kernel(
    u16* __restrict__ qkvl, const float* __restrict__ tnw, const float* __restrict__ tnb,
    const float* __restrict__ lrb, float* __restrict__ eto)
{
  int row = blockIdx.x;              // b*2048 + l
  int l = row & 2047;
  int h = threadIdx.x >> 6;
  int d = threadIdx.x & 63;
  u16* rp = qkvl + (size_t)row*3200;
  float q = bf2f(rp[h*64+d]);
  float k = bf2f(rp[1024 + h*64+d]);
  float v = bf2f(rp[2048 + h*64+d]);
  float nq = q*q, nk = k*k;
  #pragma unroll
  for (int off=1; off<64; off<<=1){ nq += __shfl_xor(nq, off); nk += __shfl_xor(nk, off); }
  q = q / fmaxf(sqrtf(nq), 1e-12f);
  k = k / fmaxf(sqrtf(nk), 1e-12f);
  int pos = l & 63;
  float invf = __expf((float)(d&31) * -0.2878231366f);   // ln(10000)/32
  float f = (float)pos * invf;
  float sn, cs; sincosf(f, &sn, &cs);
  float qp = __shfl_xor(q, 32), kp = __shfl_xor(k, 32);
  float qr = q*cs + ((d<32) ? -qp : qp)*sn;
  float kr = k*cs + ((d<32) ? -kp : kp)*sn;
  float dv = v - kr;
  float mu = dv;
  #pragma unroll
  for (int off=1; off<64; off<<=1) mu += __shfl_xor(mu, off);
  mu *= (1.f/64.f);
  float cdv = dv - mu;
  float s2 = cdv*cdv;
  #pragma unroll
  for (int off=1; off<64; off<<=1) s2 += __shfl_xor(s2, off);
  float sd = sqrtf(s2 * (1.f/63.f));
  float tgt = tnw[h*64+d]*cdv/(sd + 1e-8f) + tnb[h*64+d];
  float lgt = bf2f(rp[3072+h]) + lrb[h];
  rp[h*64+d]        = f2bf(qr);
  rp[1024 + h*64+d] = f2bf(kr);
  rp[2048 + h*64+d] = f2bf(tgt);
  if (d == 0)
    eto[(size_t)((row>>11)*16 + h)*2048 + l] = (1.f/(1.f+__expf(-lgt))) * (1.f/64.f);
}

// ---------------------------------------------------------------- TTT scan: one block per (b,h), 8 waves
// R17 base (512t / 128 VGPR, masters bf16 in LDS, anti-LICM opaque index copies,
// t-affine swizzle, Attn1 fused into S1). R18: 1-op f2bf (v_cvt_pk_bf16_f32) and
// division-free clamp-free tanh — ~35% of scan VALU removed.
__global__ __launch_bounds__(512) void scan_kernel(
    u16* __restrict__ qkvl, const float* __restrict__ etg,
    const float* __restrict__ W1g, const float* __restrict__ b1g,
    const float* __restrict__ W2g, const float* __restrict__ b2g,
    const float* __restrict__ tnw, const float* __restrict__ tnb)
{
  __shared__ __align__(16) u16 tW1[16384];   // [256][64] W1^T swizzled, bf16 master
  __shared__ __align__(16) u16 tW2[16384];   // [64][256] W2^T swizzled, bf16 master
  __shared__ __align__(16) u16 sX2[16384];   // [64][256]
  __shared__ __align__(16) u16 tG1[16384];   // [256][64] gZ1^T; reused as X2bar [64][256]
  __shared__ __align__(16) u16 sXk[4096];    // [64][64]
  __shared__ __align__(16) u16 tG2[4096];    // [64][64] gZ2^T
  __shared__ __align__(16) u16 sM[4096];     // [64][64]
  __shared__ float b1f[256];
  __shared__ float b2f[64];
  __shared__ float Et[64];
  __shared__ float gwv[64], gbv[64];
  __shared__ float st1[64][4];
  __shared__ float st2[64][4];

  const int tid0 = threadIdx.x;
  const int lr0 = tid0 & 15;
  const int lg0 = (tid0 & 63) >> 4;
  const int wid0 = tid0 >> 6;   // 0..7
  const int mtw0 = wid0 >> 1;   // 0..3
  const int nw0  = wid0 & 1;    // 0..1
  const int bh = blockIdx.x;
  const int h = bh & 15;
  const int b = bh >> 4;
  const f4 ZV = {0.f, 0.f, 0.f, 0.f};

  if (tid0 < 64){ gwv[tid0] = tnw[h*64+tid0]; gbv[tid0] = tnb[h*64+tid0]; b2f[tid0] = b2g[h*64+tid0]; }
  if (tid0 < 256) b1f[tid0] = b1g[h*256+tid0];

  #pragma unroll
  for (int t=0;t<8;++t){
    sh4 p1, p2;
    #pragma unroll
    for (int r=0;r<4;++r){
      p1[r] = (short)f2bf(W1g[(size_t)h*16384 + (mtw0*16+lg0*4+r)*256 + (nw0*8+t)*16+lr0]);
      p2[r] = (short)f2bf(W2g[(size_t)h*16384 + ((2*wid0+(t&1))*16+lg0*4+r)*64 + (t>>1)*16+lr0]);
    }
    *(sh4*)&tW1[IDX((nw0*8+t)*16+lr0, mtw0*16+lg0*4, 64)] = p1;
    *(sh4*)&tW2[IDX((t>>1)*16+lr0, (2*wid0+(t&1))*16+lg0*4, 256)] = p2;
  }
  __syncthreads();

  u16* qb = qkvl + (size_t)(b*2048)*3200 + h*64;
  const float* etb = etg + (size_t)bh*2048;

  for (int c=0; c<32; ++c){
    // Anti-LICM: every derived LDS/global address is loop-variant -> recomputed
    // per chunk (cheap VALU) instead of hoisted+spilled (the R10 pathology).
    int tid = tid0, lr = lr0, lg = lg0, mtw = mtw0, nw = nw0, wid = wid0;
    asm volatile("" : "+v"(tid), "+v"(lr), "+v"(lg), "+v"(mtw), "+v"(nw), "+v"(wid));

    u16* xq = qb + (size_t)c*64*3200;
    const u16* xk = xq + 1024;
    const u16* tg = xq + 2048;
    u16* yrow = xq + 2048;

    { // stage xk (swizzled) + eta
      int r = tid>>3, c0 = (tid&7)*8;
      bf8 vv = *(const bf8*)(xk + (size_t)r*3200 + c0);
      *(bf8*)&sXk[IDX(r, c0, 64)] = vv;
      if (tid < 64) Et[tid] = etb[c*64 + tid];
    }
    // xq fragments + targets (global, L2-hot; used in the fused S1 phase and S5)
    bf8 aq0 = *(const bf8*)(xq + (size_t)(mtw*16+lr)*3200 + lg*8);
    bf8 aq1 = *(const bf8*)(xq + (size_t)(mtw*16+lr)*3200 + 32 + lg*8);
    u16 tgp[2][4];
    #pragma unroll
    for (int n=0;n<2;++n)
      #pragma unroll
      for (int r=0;r<4;++r)
        tgp[n][r] = tg[(size_t)(mtw*16+lg*4+r)*3200 + (nw*2+n)*16+lr];
    __syncthreads();
    SB();

    // ---- S1 (+fused Attn1): Z1 = xk@W1 + b1 ; X2 = gelu(Z1) -> sX2 ;
    //      Attn1 = tril(xq@xk^T) -> M1 -> sM (sM not read until S5)
    {
      f4 acc1[8];
      #pragma unroll
      for (int t=0;t<8;++t) acc1[t] = ZV;
      #pragma unroll
      for (int kc=0; kc<2; ++kc){
        bf8 a = *(const bf8*)&sXk[IDX(mtw*16+lr, kc*32+lg*8, 64)];
        #pragma unroll
        for (int t=0;t<8;++t){
          bf8 bb = *(const bf8*)&tW1[IDX((nw*8+t)*16+lr, kc*32+lg*8, 64)];
          acc1[t] = MFMA16(a, bb, acc1[t]);
        }
      }
      f4 accA[2];
      accA[0] = ZV; accA[1] = ZV;
      #pragma unroll
      for (int kc=0; kc<2; ++kc){
        bf8 a = kc ? aq1 : aq0;
        #pragma unroll
        for (int n=0;n<2;++n){
          bf8 bb = *(const bf8*)&sXk[IDX((nw*2+n)*16+lr, kc*32+lg*8, 64)];
          accA[n] = MFMA16(a, bb, accA[n]);
        }
      }
      SB();
      #pragma unroll
      for (int t=0;t<8;++t){
        int col = (nw*8+t)*16 + lr;
        float bias = b1f[col];
        #pragma unroll
        for (int r=0;r<4;++r)
          sX2[IDX(mtw*16+lg*4+r, col, 256)] = f2bf(gelu_f(acc1[t][r] + bias));
      }
      #pragma unroll
      for (int n=0;n<2;++n){
        int col = (nw*2+n)*16+lr;
        float e = Et[col];
        #pragma unroll
        for (int r=0;r<4;++r){
          int row = mtw*16+lg*4+r;
          float m = (col <= row) ? (-e * (accA[n][r] + 1.f)) : 0.f;
          sM[IDX(row, col, 64)] = f2bf(m);
        }
      }
    }
    __syncthreads();
    SB();

    // ---- S2: Z2 = X2@W2 + b2
    f4 acc2[2];
    acc2[0] = ZV; acc2[1] = ZV;
    #pragma unroll
    for (int kc=0; kc<8; ++kc){
      bf8 a = *(const bf8*)&sX2[IDX(mtw*16+lr, kc*32+lg*8, 256)];
      #pragma unroll
      for (int n=0;n<2;++n){
        bf8 bb = *(const bf8*)&tW2[IDX((nw*2+n)*16+lr, kc*32+lg*8, 256)];
        acc2[n] = MFMA16(a, bb, acc2[n]);
      }
    }
    SB();
    {
      float ps[4], pq[4];
      #pragma unroll
      for (int r=0;r<4;++r){ ps[r]=0.f; pq[r]=0.f; }
      #pragma unroll
      for (int n=0;n<2;++n){
        float bias0 = b2f[(nw*2+n)*16+lr];
        #pragma unroll
        for (int r=0;r<4;++r){
          acc2[n][r] += bias0;
          ps[r] += acc2[n][r];
          pq[r] += acc2[n][r]*acc2[n][r];
        }
      }
      #pragma unroll
      for (int r=0;r<4;++r)
        #pragma unroll
        for (int off=1; off<16; off<<=1){ ps[r] += __shfl_xor(ps[r], off); pq[r] += __shfl_xor(pq[r], off); }
      if (lr == 0){
        #pragma unroll
        for (int r=0;r<4;++r){ st1[mtw*16+lg*4+r][nw*2] = ps[r]; st1[mtw*16+lg*4+r][nw*2+1] = pq[r]; }
      }
    }
    __syncthreads();
    SB();
    float gy[2][4], xh[2][4];
    {
      float pg[4], ph[4];
      #pragma unroll
      for (int r=0;r<4;++r){ pg[r]=0.f; ph[r]=0.f; }
      #pragma unroll
      for (int n=0;n<2;++n){
        int col = (nw*2+n)*16+lr;
        float g = gwv[col], bb = gbv[col];
        #pragma unroll
        for (int r=0;r<4;++r){
          int row = mtw*16+lg*4+r;
          float s1 = st1[row][0] + st1[row][2];
          float s2 = st1[row][1] + st1[row][3];
          float muv = s1 * (1.f/64.f);
          float rsv = rsqrtf(s2*(1.f/64.f) - muv*muv + 1e-6f);
          float x = (acc2[n][r] - muv) * rsv;
          float t = bf2f(tgp[n][r]);
          float gyv = (g*x + bb - t) * g;
          gy[n][r] = gyv; xh[n][r] = x;
          pg[r] += gyv; ph[r] += gyv*x;
        }
      }
      #pragma unroll
      for (int r=0;r<4;++r)
        #pragma unroll
        for (int off=1; off<16; off<<=1){ pg[r] += __shfl_xor(pg[r], off); ph[r] += __shfl_xor(ph[r], off); }
      if (lr == 0){
        #pragma unroll
        for (int r=0;r<4;++r){ st2[mtw*16+lg*4+r][nw*2] = pg[r]; st2[mtw*16+lg*4+r][nw*2+1] = ph[r]; }
      }
    }
    __syncthreads();
    SB();
    #pragma unroll
    for (int n=0;n<2;++n){
      int col = (nw*2+n)*16+lr;
      sh4 pk;
      #pragma unroll
      for (int r=0;r<4;++r){
        int row = mtw*16+lg*4+r;
        float s1 = st1[row][0] + st1[row][2];
        float s2 = st1[row][1] + st1[row][3];
        float muv = s1 * (1.f/64.f);
        float rsv = rsqrtf(s2*(1.f/64.f) - muv*muv + 1e-6f);   // bit-identical recompute
        float sg = st2[row][0] + st2[row][2];
        float sx = st2[row][1] + st2[row][3];
        float gz = (64.f*gy[n][r] - sg - xh[n][r]*sx) * (rsv * (1.f/64.f));
        pk[r] = (short)f2bf(gz);
      }
      *(sh4*)&tG2[IDX(col, mtw*16+lg*4, 64)] = pk;
    }
    __syncthreads();
    SB();

    // ---- S3: gZ1 = (gZ2 @ W2^T) * gelu_bwd(Z1); Z1 recomputed bit-identically
    {
      f4 acc3[8];
      #pragma unroll
      for (int t=0;t<8;++t) acc3[t] = ZV;
      #pragma unroll
      for (int kc=0; kc<2; ++kc){
        int k0 = kc*32 + lg*8;
        bf8 a;
        #pragma unroll
        for (int j=0;j<8;++j) a[j] = (short)tG2[IDX(k0+j, mtw*16+lr, 64)];
        #pragma unroll
        for (int t=0;t<8;++t){
          bf8 bb;
          #pragma unroll
          for (int j=0;j<8;++j) bb[j] = (short)tW2[IDX(k0+j, (nw*8+t)*16+lr, 256)];
          acc3[t] = MFMA16(a, bb, acc3[t]);
        }
      }
      SB();
      bf8 xk0 = *(const bf8*)&sXk[IDX(mtw*16+lr, 0*32+lg*8, 64)];
      bf8 xk1 = *(const bf8*)&sXk[IDX(mtw*16+lr, 1*32+lg*8, 64)];
      #pragma unroll
      for (int t=0;t<8;++t){
        int col = (nw*8+t)*16+lr;
        f4 z = ZV;
        z = MFMA16(xk0, *(const bf8*)&tW1[IDX(col, 0*32+lg*8, 64)], z);
        z = MFMA16(xk1, *(const bf8*)&tW1[IDX(col, 1*32+lg*8, 64)], z);
        float bias = b1f[col];
        sh4 pk;
        #pragma unroll
        for (int r=0;r<4;++r) pk[r] = (short)f2bf(acc3[t][r] * gelu_bwd_f(z[r] + bias));
        *(sh4*)&tG1[IDX(col, mtw*16+lg*4, 64)] = pk;
      }
    }
    __syncthreads();
    SB();

    // ---- S5: Z1_bar = xq@W1(old) + M1@gZ1 + b1 ; pack X2_bar bf16 immediately
    sh4 X2bp[8];
    {
      f4 acc4[8];
      #pragma unroll
      for (int t=0;t<8;++t) acc4[t] = ZV;
      #pragma unroll
      for (int kc=0; kc<2; ++kc){
        bf8 a = kc ? aq1 : aq0;
        #pragma unroll
        for (int t=0;t<8;++t){
          bf8 bb = *(const bf8*)&tW1[IDX((nw*8+t)*16+lr, kc*32+lg*8, 64)];
          acc4[t] = MFMA16(a, bb, acc4[t]);
        }
      }
      #pragma unroll
      for (int kc=0; kc<2; ++kc){
        bf8 a = *(const bf8*)&sM[IDX(mtw*16+lr, kc*32+lg*8, 64)];
        #pragma unroll
        for (int t=0;t<8;++t){
          bf8 bb = *(const bf8*)&tG1[IDX((nw*8+t)*16+lr, kc*32+lg*8, 64)];
          acc4[t] = MFMA16(a, bb, acc4[t]);
        }
      }
      SB();
      #pragma unroll
      for (int t=0;t<8;++t){
        float bias = b1f[(nw*8+t)*16+lr];
        #pragma unroll
        for (int r=0;r<4;++r) X2bp[t][r] = (short)f2bf(gelu_f(acc4[t][r] + bias));
      }
    }
    SB();
    // ---- S6': W1n = tW1(old) + (-eta*xk)^T @ gZ1 ; b1 colsum via Et-broadcast MFMA
    f4 W1n[8]; float b1d[8];
    #pragma unroll
    for (int t=0;t<8;++t){
      sh4 cf = *(const sh4*)&tW1[IDX((nw*8+t)*16+lr, mtw*16+lg*4, 64)];
      #pragma unroll
      for (int r=0;r<4;++r) W1n[t][r] = bf2f((u16)cf[r]);
    }
    SB();
    #pragma unroll
    for (int kc=0; kc<2; ++kc){
      int k0 = kc*32 + lg*8;
      bf8 xa, ea;
      #pragma unroll
      for (int j=0;j<8;++j){
        float e = Et[k0+j];
        ea[j] = (short)f2bf(e);
        xa[j] = (short)f2bf(-bf2f(sXk[IDX(k0+j, mtw*16+lr, 64)]) * e);
      }
      #pragma unroll
      for (int t=0;t<8;++t){
        bf8 bb = *(const bf8*)&tG1[IDX((nw*8+t)*16+lr, kc*32+lg*8, 64)];
        W1n[t] = MFMA16(xa, bb, W1n[t]);
        f4 d0 = ZV;
        d0 = MFMA16(ea, bb, d0);
        if (kc==0) b1d[t] = d0[0]; else b1d[t] += d0[0];
      }
    }
    __syncthreads();
    SB();
    // commit new W1 (bf16), write X2_bar over tG1, apply b1 delta
    u16* X2b = tG1;
    #pragma unroll
    for (int t=0;t<8;++t){
      int col = (nw*8+t)*16+lr;
      sh4 p1;
      #pragma unroll
      for (int r=0;r<4;++r){
        X2b[IDX(mtw*16+lg*4+r, col, 256)] = (u16)X2bp[t][r];
        p1[r] = (short)f2bf(W1n[t][r]);
      }
      *(sh4*)&tW1[IDX(col, mtw*16+lg*4, 64)] = p1;
    }
    if (mtw == 0 && lg == 0){
      #pragma unroll
      for (int t=0;t<8;++t) b1f[(nw*8+t)*16+lr] -= b1d[t];
    }
    __syncthreads();
    SB();

    // ---- S7: Attn2 -> M2
    {
      f4 accB[2];
      accB[0] = ZV; accB[1] = ZV;
      #pragma unroll
      for (int kc=0; kc<8; ++kc){
        bf8 a = *(const bf8*)&X2b[IDX(mtw*16+lr, kc*32+lg*8, 256)];
        #pragma unroll
        for (int n=0;n<2;++n){
          bf8 bb = *(const bf8*)&sX2[IDX((nw*2+n)*16+lr, kc*32+lg*8, 256)];
          accB[n] = MFMA16(a, bb, accB[n]);
        }
      }
      SB();
      #pragma unroll
      for (int n=0;n<2;++n){
        int col = (nw*2+n)*16+lr;
        float e = Et[col];
        #pragma unroll
        for (int r=0;r<4;++r){
          int row = mtw*16+lg*4+r;
          float m = (col <= row) ? (-e * (accB[n][r] + 1.f)) : 0.f;
          sM[IDX(row, col, 64)] = f2bf(m);
        }
      }
    }
    __syncthreads();
    SB();

    // ---- S8: Z2_bar = X2_bar@W2 + M2@gZ2 + b2 (acc6)
    f4 acc6[2];
    acc6[0] = ZV; acc6[1] = ZV;
    #pragma unroll
    for (int kc=0; kc<8; ++kc){
      bf8 a = *(const bf8*)&X2b[IDX(mtw*16+lr, kc*32+lg*8, 256)];
      #pragma unroll
      for (int n=0;n<2;++n){
        bf8 bb = *(const bf8*)&tW2[IDX((nw*2+n)*16+lr, kc*32+lg*8, 256)];
        acc6[n] = MFMA16(a, bb, acc6[n]);
      }
    }
    #pragma unroll
    for (int kc=0; kc<2; ++kc){
      bf8 a = *(const bf8*)&sM[IDX(mtw*16+lr, kc*32+lg*8, 64)];
      #pragma unroll
      for (int n=0;n<2;++n){
        bf8 bb = *(const bf8*)&tG2[IDX((nw*2+n)*16+lr, kc*32+lg*8, 64)];
        acc6[n] = MFMA16(a, bb, acc6[n]);
      }
    }
    SB();
    #pragma unroll
    for (int n=0;n<2;++n){
      float bias0 = b2f[(nw*2+n)*16+lr];
      #pragma unroll
      for (int r=0;r<4;++r) acc6[n][r] += bias0;
    }
    SB();
    // ---- S9': W2n = tW2(old) + (-eta*X2)^T @ gZ2 ; b2 colsum via Et-broadcast MFMA
    f4 W2n[8]; float b2d[2];
    #pragma unroll
    for (int t=0;t<8;++t){
      sh4 cf = *(const sh4*)&tW2[IDX((t>>1)*16+lr, (2*wid+(t&1))*16+lg*4, 256)];
      #pragma unroll
      for (int r=0;r<4;++r) W2n[t][r] = bf2f((u16)cf[r]);
    }
    SB();
    #pragma unroll
    for (int n=0;n<2;++n){
      f4 d = ZV;
      #pragma unroll
      for (int kc=0; kc<2; ++kc){
        int k0 = kc*32+lg*8;
        bf8 ea;
        #pragma unroll
        for (int j=0;j<8;++j) ea[j] = (short)f2bf(Et[k0+j]);
        bf8 bb = *(const bf8*)&tG2[IDX((nw*2+n)*16+lr, kc*32+lg*8, 64)];
        d = MFMA16(ea, bb, d);
      }
      b2d[n] = d[0];
    }
    SB();
    #pragma unroll
    for (int kc=0; kc<2; ++kc){
      int k0 = kc*32 + lg*8;
      bf8 a2[2];
      #pragma unroll
      for (int ta=0; ta<2; ++ta)
        #pragma unroll
        for (int j=0;j<8;++j) a2[ta][j] = (short)f2bf(-bf2f(sX2[IDX(k0+j, (2*wid+ta)*16+lr, 256)]) * Et[k0+j]);
      #pragma unroll
      for (int nb=0; nb<4; ++nb){
        bf8 bb = *(const bf8*)&tG2[IDX(nb*16+lr, kc*32+lg*8, 64)];
        #pragma unroll
        for (int ta=0; ta<2; ++ta) W2n[nb*2+ta] = MFMA16(a2[ta], bb, W2n[nb*2+ta]);
      }
    }
    __syncthreads();
    SB();
    // commit new W2, apply b2 delta, LN-fwd stats of Z2_bar
    #pragma unroll
    for (int t=0;t<8;++t){
      sh4 p2;
      #pragma unroll
      for (int r=0;r<4;++r) p2[r] = (short)f2bf(W2n[t][r]);
      *(sh4*)&tW2[IDX((t>>1)*16+lr, (2*wid+(t&1))*16+lg*4, 256)] = p2;
    }
    if (mtw == 0 && lg == 0){
      #pragma unroll
      for (int n=0;n<2;++n) b2f[(nw*2+n)*16+lr] -= b2d[n];
    }
    SB();
    {
      float ps[4], pq[4];
      #pragma unroll
      for (int r=0;r<4;++r){ ps[r]=0.f; pq[r]=0.f; }
      #pragma unroll
      for (int n=0;n<2;++n)
        #pragma unroll
        for (int r=0;r<4;++r){ ps[r] += acc6[n][r]; pq[r] += acc6[n][r]*acc6[n][r]; }
      #pragma unroll
      for (int r=0;r<4;++r)
        #pragma unroll
        for (int off=1; off<16; off<<=1){ ps[r] += __shfl_xor(ps[r], off); pq[r] += __shfl_xor(pq[r], off); }
      if (lr == 0){
        #pragma unroll
        for (int r=0;r<4;++r){ st1[mtw*16+lg*4+r][nw*2] = ps[r]; st1[mtw*16+lg*4+r][nw*2+1] = pq[r]; }
      }
    }
    __syncthreads();
    SB();
    // ---- S10: out = xq + ln_fwd(Z2_bar) (in place over target cols)
    #pragma unroll
    for (int r=0;r<4;++r){
      int row = mtw*16+lg*4+r;
      float s1 = st1[row][0] + st1[row][2];
      float s2 = st1[row][1] + st1[row][3];
      float m = s1 * (1.f/64.f);
      float rstd = rsqrtf(s2*(1.f/64.f) - m*m + 1e-6f);
      size_t ro = (size_t)row*3200;
      #pragma unroll
      for (int n=0;n<2;++n){
        int col = (nw*2+n)*16+lr;
        float val = bf2f(xq[ro+col]) + gwv[col]*(acc6[n][r]-m)*rstd + gbv[col];
        yrow[ro+col] = f2bf(val);
      }
    }
    __syncthreads();
  }
}

// ---------------------------------------------------------------- post layernorm over D=1024 (in place)
__global__ __launch_bounds__(256) void postln_kernel(u16* __restrict__ qkvl,
    const float* __restrict__ pw, const float* __restrict__ pb)
{
  int row = blockIdx.x;
  u16* rp = qkvl + (size_t)row*3200;
  float v[4]; float s1=0.f, s2=0.f;
  #pragma unroll
  for (int i=0;i<4;++i){ v[i] = bf2f(rp[2048 + threadIdx.x + i*256]); s1 += v[i]; s2 += v[i]*v[i]; }
  #pragma unroll
  for (int off=1; off<64; off<<=1){ s1 += __shfl_xor(s1, off); s2 += __shfl_xor(s2, off); }
  __shared__ float r1[4], r2[4];
  int w = threadIdx.x >> 6;
  if ((threadIdx.x & 63) == 0){ r1[w] = s1; r2[w] = s2; }
  __syncthreads();
  s1 = r1[0]+r1[1]+r1[2]+r1[3];
  s2 = r2[0]+r2[1]+r2[2]+r2[3];
  float mu = s1*(1.f/1024.f);
  float rstd = rsqrtf(s2*(1.f/1024.f) - mu*mu + 1e-6f);
  #pragma unroll
  for (int i=0;i<4;++i){
    int col = threadIdx.x + i*256;
    rp[col] = f2bf(pw[col]*(v[i]-mu)*rstd + pb[col]);
  }
}

// ---------------------------------------------------------------- launch
extern "C" void kernel_launch(void* const* d_in, const int* in_sizes, int n_in,
                              void* d_out, int out_size, void* d_ws, size_t ws_size,
                              hipStream_t stream)
{
  const float* x   = (const float*)d_in[0];
  const float* Wq  = (const float*)d_in[1];
  const float* Wk  = (const float*)d_in[2];
  const float* Wv  = (const float*)d_in[3];
  const float* Wo  = (const float*)d_in[4];
  const float* W1  = (const float*)d_in[5];
  const float* b1  = (const float*)d_in[6];
  const float* W2  = (const float*)d_in[7];
  const float* b2  = (const float*)d_in[8];
  const float* tnw = (const float*)d_in[9];
  const float* tnb = (const float*)d_in[10];
  const float* lrw = (const float*)d_in[11];
  const float* lrb = (const float*)d_in[12];
  const float* pnw = (const float*)d_in[13];
  const float* pnb = (const float*)d_in[14];
  (void)in_sizes; (void)n_in; (void)out_size; (void)ws_size;

  u16* qkvl  = (u16*)d_ws;                       // [8192][3200] bf16 = 50 MB
  u16* wcat  = (u16*)d_out;                      // d_out scratch; dead before final GEMM
  float* etg = (float*)((char*)d_out + 6553600);

  convert_kernel<<<1024, 256, 0, stream>>>(Wq, Wk, Wv, lrw, wcat);
  gemm_kernel<1,0,0><<<dim3(25, 64), 256, 0, stream>>>(x, wcat, qkvl, 8192, 3200, 1024, 1024, 1024, 3200);
  postproc_kernel<<<8192, 1024, 0, stream>>>(qkvl, tnw, tnb, lrb, etg);
  scan_kernel<<<64, 512, 0, stream>>>(qkvl, etg, W1, b1, W2, b2, tnw, tnb);
  postln_kernel<<<8192, 256, 0, stream>>>(qkvl, pnw, pnb);
  gemm_kernel<0,1,1><<<dim3(8, 64), 256, 0, stream>>>(qkvl, Wo, d_out, 8192, 1024, 1024, 3200, 1024, 1024);
}

// Round 19
// 852.922 us; speedup vs baseline: 1.8896x; 1.0626x over previous
//
#include <hip/hip_runtime.h>

typedef unsigned short u16;
typedef __attribute__((ext_vector_type(8))) short bf8;
typedef __attribute__((ext_vector_type(4))) short sh4;
typedef __attribute__((ext_vector_type(4))) float f4;
typedef __attribute__((ext_vector_type(2))) unsigned int u32x2;
typedef __attribute__((ext_vector_type(4))) unsigned int u32x4;

#define MFMA16(a,b,c) __builtin_amdgcn_mfma_f32_16x16x32_bf16((a),(b),(c),0,0,0)
#define SB() __builtin_amdgcn_sched_barrier(0)

__device__ __forceinline__ float bf2f(u16 u){ return __uint_as_float(((unsigned)u)<<16); }
// HW RNE bf16 conversion (1 VALU op).
__device__ __forceinline__ u16 f2bf(float f){
  unsigned r;
  asm("v_cvt_pk_bf16_f32 %0, %1, %1" : "=v"(r) : "v"(f));
  return (u16)r;
}
// Pack TWO floats -> one u32 of 2 bf16 (lo=S0, hi=S1) in a single VALU op.
__device__ __forceinline__ unsigned pk2(float lo, float hi){
  unsigned r;
  asm("v_cvt_pk_bf16_f32 %0, %1, %2" : "=v"(r) : "v"(lo), "v"(hi));
  return r;
}
__device__ __forceinline__ void store_pk4(u16* dst, float a, float b, float c, float d){
  u32x2 p; p[0] = pk2(a,b); p[1] = pk2(c,d);
  *(u32x2*)dst = p;
}
union bfu { bf8 v; u32x4 u; };

// gelu via sigmoid identity: 0.5*(1+tanh(C*u)) = sigmoid(2*C*u).
#define GELU_C 0.7978845608028654f
#define GK2    1.5957691216057308f   /* 2*GELU_C */
__device__ __forceinline__ float gelu_f(float x){
  float u = x + 0.044715f*x*x*x;
  float s = __builtin_amdgcn_rcpf(1.f + __expf(-GK2*u));
  return x*s;
}
__device__ __forceinline__ float gelu_bwd_f(float x){
  float x2 = x*x;
  float u = x + 0.044715f*x2*x;
  float s = __builtin_amdgcn_rcpf(1.f + __expf(-GK2*u));
  return s + x*(2.f*s*(1.f-s))*GELU_C*(1.f + 0.134145f*x2);
}

// Scan-kernel LDS swizzle: f = r&7 (t-affine; folds into ds offset immediates).
__device__ __forceinline__ int IDX(int r, int c, int ldc){
  int f = r & 7;
  return r*ldc + ((((c>>3) ^ f)<<3) | (c&7));
}

// ---------------------------------------------------------------- convert: build wcat in d_out scratch
__global__ void convert_kernel(const float* __restrict__ Wq, const float* __restrict__ Wk,
    const float* __restrict__ Wv, const float* __restrict__ lrw, u16* __restrict__ wcat)
{
  size_t i0 = (size_t)blockIdx.x*blockDim.x + threadIdx.x;
  size_t stride = (size_t)gridDim.x*blockDim.x;
  for (size_t i=i0; i<3276800u; i+=stride){
    int n = (int)(i>>10);
    float v;
    if (n < 1024) v = Wq[i];
    else if (n < 2048) v = Wk[i - 1048576u];
    else if (n < 3072) v = Wv[i - 2097152u];
    else if (n < 3088) v = lrw[i - 3145728u];
    else v = 0.f;
    wcat[i] = f2bf(v);
  }
}

// ---------------------------------------------------------------- GEMM  C[M,N] = A[M,K] @ B[N,K]^T
template<int AF32, int BF32, int COUT>
__global__ __launch_bounds__(256) void gemm_kernel(const void* __restrict__ Ap, const void* __restrict__ Bp,
    void* __restrict__ C, int M, int N, int K, int lda, int ldb, int ldc)
{
  __shared__ __align__(16) u16 sA[128*64];
  __shared__ __align__(16) u16 sB[128*64];
  const int tid = threadIdx.x;
  const int lane = tid & 63, wid = tid >> 6;
  const int lr = lane & 15, lg = lane >> 4;
  const int wm = wid >> 1, wn = wid & 1;
  const int m0 = blockIdx.y*128, n0 = blockIdx.x*128;
  f4 acc[4][4];
  #pragma unroll
  for (int mi=0;mi<4;++mi)
    #pragma unroll
    for (int ni=0;ni<4;++ni){ acc[mi][ni][0]=0.f; acc[mi][ni][1]=0.f; acc[mi][ni][2]=0.f; acc[mi][ni][3]=0.f; }
  for (int k0=0; k0<K; k0+=64){
    #pragma unroll
    for (int i=0;i<4;++i){
      int cid = i*256 + tid;
      int row = cid>>3, cc = cid&7;
      int sl = cc ^ (row&7);
      bf8 pa, pb;
      if (AF32){
        const float* p = (const float*)Ap + (size_t)(m0+row)*lda + k0 + cc*8;
        #pragma unroll
        for (int j=0;j<8;++j) pa[j] = (short)f2bf(p[j]);
      } else {
        pa = *(const bf8*)((const u16*)Ap + (size_t)(m0+row)*lda + k0 + cc*8);
      }
      if (BF32){
        const float* p = (const float*)Bp + (size_t)(n0+row)*ldb + k0 + cc*8;
        #pragma unroll
        for (int j=0;j<8;++j) pb[j] = (short)f2bf(p[j]);
      } else {
        pb = *(const bf8*)((const u16*)Bp + (size_t)(n0+row)*ldb + k0 + cc*8);
      }
      *(bf8*)&sA[row*64 + sl*8] = pa;
      *(bf8*)&sB[row*64 + sl*8] = pb;
    }
    __syncthreads();
    #pragma unroll
    for (int kc=0;kc<2;++kc){
      bf8 av[4], bv[4];
      #pragma unroll
      for (int i=0;i<4;++i){
        int ra = wm*64 + i*16 + lr;
        av[i] = *(const bf8*)&sA[ra*64 + ((kc*4+lg)^(ra&7))*8];
        int rb = wn*64 + i*16 + lr;
        bv[i] = *(const bf8*)&sB[rb*64 + ((kc*4+lg)^(rb&7))*8];
      }
      #pragma unroll
      for (int mi=0;mi<4;++mi)
        #pragma unroll
        for (int ni=0;ni<4;++ni)
          acc[mi][ni] = MFMA16(av[mi], bv[ni], acc[mi][ni]);
    }
    __syncthreads();
  }
  #pragma unroll
  for (int mi=0;mi<4;++mi)
    #pragma unroll
    for (int ni=0;ni<4;++ni)
      #pragma unroll
      for (int r=0;r<4;++r){
        int row = m0 + wm*64 + mi*16 + lg*4 + r;
        int col = n0 + wn*64 + ni*16 + lr;
        if (COUT) ((float*)C)[(size_t)row*ldc + col] = acc[mi][ni][r];
        else ((u16*)C)[(size_t)row*ldc + col] = f2bf(acc[mi][ni][r]);
      }
}

// ---------------------------------------------------------------- postprocess IN PLACE on qkvl rows
__global__ __launch_bounds__(1024) void postproc_kernel(
    u16* __restrict__ qkvl, const float* __restrict__ tnw, const float* __restrict__ tnb,
    const float* __restrict__ lrb, float* __restrict__ eto)
{
  int row = blockIdx.x;              // b*2048 + l
  int l = row & 2047;
  int h = threadIdx.x >> 6;
  int d = threadIdx.x & 63;
  u16* rp = qkvl + (size_t)row*3200;
  float q = bf2f(rp[h*64+d]);
  float k = bf2f(rp[1024 + h*64+d]);
  float v = bf2f(rp[2048 + h*64+d]);
  float nq = q*q, nk = k*k;
  #pragma unroll
  for (int off=1; off<64; off<<=1){ nq += __shfl_xor(nq, off); nk += __shfl_xor(nk, off); }
  q = q / fmaxf(sqrtf(nq), 1e-12f);
  k = k / fmaxf(sqrtf(nk), 1e-12f);
  int pos = l & 63;
  float invf = __expf((float)(d&31) * -0.2878231366f);   // ln(10000)/32
  float f = (float)pos * invf;
  float sn, cs; sincosf(f, &sn, &cs);
  float qp = __shfl_xor(q, 32), kp = __shfl_xor(k, 32);
  float qr = q*cs + ((d<32) ? -qp : qp)*sn;
  float kr = k*cs + ((d<32) ? -kp : kp)*sn;
  float dv = v - kr;
  float mu = dv;
  #pragma unroll
  for (int off=1; off<64; off<<=1) mu += __shfl_xor(mu, off);
  mu *= (1.f/64.f);
  float cdv = dv - mu;
  float s2 = cdv*cdv;
  #pragma unroll
  for (int off=1; off<64; off<<=1) s2 += __shfl_xor(s2, off);
  float sd = sqrtf(s2 * (1.f/63.f));
  float tgt = tnw[h*64+d]*cdv/(sd + 1e-8f) + tnb[h*64+d];
  float lgt = bf2f(rp[3072+h]) + lrb[h];
  rp[h*64+d]        = f2bf(qr);
  rp[1024 + h*64+d] = f2bf(kr);
  rp[2048 + h*64+d] = f2bf(tgt);
  if (d == 0)
    eto[(size_t)((row>>11)*16 + h)*2048 + l] = (1.f/(1.f+__expf(-lgt))) * (1.f/64.f);
}

// ---------------------------------------------------------------- TTT scan: one block per (b,h), 8 waves
// R18 base (512t / 128 VGPR, LDS masters, anti-LICM, t-affine swizzle, fused Attn1,
// 1-op f2bf, fast tanh). R19: sigmoid-form gelu (no tanh intermediate) and paired
// bf16 conversion (v_cvt_pk_bf16_f32 with two sources) at all pack sites.
__global__ __launch_bounds__(512) void scan_kernel(
    u16* __restrict__ qkvl, const float* __restrict__ etg,
    const float* __restrict__ W1g, const float* __restrict__ b1g,
    const float* __restrict__ W2g, const float* __restrict__ b2g,
    const float* __restrict__ tnw, const float* __restrict__ tnb)
{
  __shared__ __align__(16) u16 tW1[16384];   // [256][64] W1^T swizzled, bf16 master
  __shared__ __align__(16) u16 tW2[16384];   // [64][256] W2^T swizzled, bf16 master
  __shared__ __align__(16) u16 sX2[16384];   // [64][256]
  __shared__ __align__(16) u16 tG1[16384];   // [256][64] gZ1^T; reused as X2bar [64][256]
  __shared__ __align__(16) u16 sXk[4096];    // [64][64]
  __shared__ __align__(16) u16 tG2[4096];    // [64][64] gZ2^T
  __shared__ __align__(16) u16 sM[4096];     // [64][64]
  __shared__ float b1f[256];
  __shared__ float b2f[64];
  __shared__ float Et[64];
  __shared__ float gwv[64], gbv[64];
  __shared__ float st1[64][4];
  __shared__ float st2[64][4];

  const int tid0 = threadIdx.x;
  const int lr0 = tid0 & 15;
  const int lg0 = (tid0 & 63) >> 4;
  const int wid0 = tid0 >> 6;   // 0..7
  const int mtw0 = wid0 >> 1;   // 0..3
  const int nw0  = wid0 & 1;    // 0..1
  const int bh = blockIdx.x;
  const int h = bh & 15;
  const int b = bh >> 4;
  const f4 ZV = {0.f, 0.f, 0.f, 0.f};

  if (tid0 < 64){ gwv[tid0] = tnw[h*64+tid0]; gbv[tid0] = tnb[h*64+tid0]; b2f[tid0] = b2g[h*64+tid0]; }
  if (tid0 < 256) b1f[tid0] = b1g[h*256+tid0];

  #pragma unroll
  for (int t=0;t<8;++t){
    float w1v[4], w2v[4];
    #pragma unroll
    for (int r=0;r<4;++r){
      w1v[r] = W1g[(size_t)h*16384 + (mtw0*16+lg0*4+r)*256 + (nw0*8+t)*16+lr0];
      w2v[r] = W2g[(size_t)h*16384 + ((2*wid0+(t&1))*16+lg0*4+r)*64 + (t>>1)*16+lr0];
    }
    store_pk4(&tW1[IDX((nw0*8+t)*16+lr0, mtw0*16+lg0*4, 64)], w1v[0],w1v[1],w1v[2],w1v[3]);
    store_pk4(&tW2[IDX((t>>1)*16+lr0, (2*wid0+(t&1))*16+lg0*4, 256)], w2v[0],w2v[1],w2v[2],w2v[3]);
  }
  __syncthreads();

  u16* qb = qkvl + (size_t)(b*2048)*3200 + h*64;
  const float* etb = etg + (size_t)bh*2048;

  for (int c=0; c<32; ++c){
    // Anti-LICM: every derived LDS/global address is loop-variant -> recomputed
    // per chunk (cheap VALU) instead of hoisted+spilled (the R10 pathology).
    int tid = tid0, lr = lr0, lg = lg0, mtw = mtw0, nw = nw0, wid = wid0;
    asm volatile("" : "+v"(tid), "+v"(lr), "+v"(lg), "+v"(mtw), "+v"(nw), "+v"(wid));

    u16* xq = qb + (size_t)c*64*3200;
    const u16* xk = xq + 1024;
    const u16* tg = xq + 2048;
    u16* yrow = xq + 2048;

    { // stage xk (swizzled) + eta
      int r = tid>>3, c0 = (tid&7)*8;
      bf8 vv = *(const bf8*)(xk + (size_t)r*3200 + c0);
      *(bf8*)&sXk[IDX(r, c0, 64)] = vv;
      if (tid < 64) Et[tid] = etb[c*64 + tid];
    }
    // xq fragments + targets (global, L2-hot; used in the fused S1 phase and S5)
    bf8 aq0 = *(const bf8*)(xq + (size_t)(mtw*16+lr)*3200 + lg*8);
    bf8 aq1 = *(const bf8*)(xq + (size_t)(mtw*16+lr)*3200 + 32 + lg*8);
    u16 tgp[2][4];
    #pragma unroll
    for (int n=0;n<2;++n)
      #pragma unroll
      for (int r=0;r<4;++r)
        tgp[n][r] = tg[(size_t)(mtw*16+lg*4+r)*3200 + (nw*2+n)*16+lr];
    __syncthreads();
    SB();

    // ---- S1 (+fused Attn1): Z1 = xk@W1 + b1 ; X2 = gelu(Z1) -> sX2 ;
    //      Attn1 = tril(xq@xk^T) -> M1 -> sM (sM not read until S5)
    {
      f4 acc1[8];
      #pragma unroll
      for (int t=0;t<8;++t) acc1[t] = ZV;
      #pragma unroll
      for (int kc=0; kc<2; ++kc){
        bf8 a = *(const bf8*)&sXk[IDX(mtw*16+lr, kc*32+lg*8, 64)];
        #pragma unroll
        for (int t=0;t<8;++t){
          bf8 bb = *(const bf8*)&tW1[IDX((nw*8+t)*16+lr, kc*32+lg*8, 64)];
          acc1[t] = MFMA16(a, bb, acc1[t]);
        }
      }
      f4 accA[2];
      accA[0] = ZV; accA[1] = ZV;
      #pragma unroll
      for (int kc=0; kc<2; ++kc){
        bf8 a = kc ? aq1 : aq0;
        #pragma unroll
        for (int n=0;n<2;++n){
          bf8 bb = *(const bf8*)&sXk[IDX((nw*2+n)*16+lr, kc*32+lg*8, 64)];
          accA[n] = MFMA16(a, bb, accA[n]);
        }
      }
      SB();
      #pragma unroll
      for (int t=0;t<8;++t){
        int col = (nw*8+t)*16 + lr;
        float bias = b1f[col];
        #pragma unroll
        for (int r=0;r<4;++r)
          sX2[IDX(mtw*16+lg*4+r, col, 256)] = f2bf(gelu_f(acc1[t][r] + bias));
      }
      #pragma unroll
      for (int n=0;n<2;++n){
        int col = (nw*2+n)*16+lr;
        float e = Et[col];
        #pragma unroll
        for (int r=0;r<4;++r){
          int row = mtw*16+lg*4+r;
          float m = (col <= row) ? (-e * (accA[n][r] + 1.f)) : 0.f;
          sM[IDX(row, col, 64)] = f2bf(m);
        }
      }
    }
    __syncthreads();
    SB();

    // ---- S2: Z2 = X2@W2 + b2
    f4 acc2[2];
    acc2[0] = ZV; acc2[1] = ZV;
    #pragma unroll
    for (int kc=0; kc<8; ++kc){
      bf8 a = *(const bf8*)&sX2[IDX(mtw*16+lr, kc*32+lg*8, 256)];
      #pragma unroll
      for (int n=0;n<2;++n){
        bf8 bb = *(const bf8*)&tW2[IDX((nw*2+n)*16+lr, kc*32+lg*8, 256)];
        acc2[n] = MFMA16(a, bb, acc2[n]);
      }
    }
    SB();
    {
      float ps[4], pq[4];
      #pragma unroll
      for (int r=0;r<4;++r){ ps[r]=0.f; pq[r]=0.f; }
      #pragma unroll
      for (int n=0;n<2;++n){
        float bias0 = b2f[(nw*2+n)*16+lr];
        #pragma unroll
        for (int r=0;r<4;++r){
          acc2[n][r] += bias0;
          ps[r] += acc2[n][r];
          pq[r] += acc2[n][r]*acc2[n][r];
        }
      }
      #pragma unroll
      for (int r=0;r<4;++r)
        #pragma unroll
        for (int off=1; off<16; off<<=1){ ps[r] += __shfl_xor(ps[r], off); pq[r] += __shfl_xor(pq[r], off); }
      if (lr == 0){
        #pragma unroll
        for (int r=0;r<4;++r){ st1[mtw*16+lg*4+r][nw*2] = ps[r]; st1[mtw*16+lg*4+r][nw*2+1] = pq[r]; }
      }
    }
    __syncthreads();
    SB();
    float gy[2][4], xh[2][4];
    {
      float pg[4], ph[4];
      #pragma unroll
      for (int r=0;r<4;++r){ pg[r]=0.f; ph[r]=0.f; }
      #pragma unroll
      for (int n=0;n<2;++n){
        int col = (nw*2+n)*16+lr;
        float g = gwv[col], bb = gbv[col];
        #pragma unroll
        for (int r=0;r<4;++r){
          int row = mtw*16+lg*4+r;
          float s1 = st1[row][0] + st1[row][2];
          float s2 = st1[row][1] + st1[row][3];
          float muv = s1 * (1.f/64.f);
          float rsv = rsqrtf(s2*(1.f/64.f) - muv*muv + 1e-6f);
          float x = (acc2[n][r] - muv) * rsv;
          float t = bf2f(tgp[n][r]);
          float gyv = (g*x + bb - t) * g;
          gy[n][r] = gyv; xh[n][r] = x;
          pg[r] += gyv; ph[r] += gyv*x;
        }
      }
      #pragma unroll
      for (int r=0;r<4;++r)
        #pragma unroll
        for (int off=1; off<16; off<<=1){ pg[r] += __shfl_xor(pg[r], off); ph[r] += __shfl_xor(ph[r], off); }
      if (lr == 0){
        #pragma unroll
        for (int r=0;r<4;++r){ st2[mtw*16+lg*4+r][nw*2] = pg[r]; st2[mtw*16+lg*4+r][nw*2+1] = ph[r]; }
      }
    }
    __syncthreads();
    SB();
    #pragma unroll
    for (int n=0;n<2;++n){
      int col = (nw*2+n)*16+lr;
      float gz[4];
      #pragma unroll
      for (int r=0;r<4;++r){
        int row = mtw*16+lg*4+r;
        float s1 = st1[row][0] + st1[row][2];
        float s2 = st1[row][1] + st1[row][3];
        float muv = s1 * (1.f/64.f);
        float rsv = rsqrtf(s2*(1.f/64.f) - muv*muv + 1e-6f);   // bit-identical recompute
        float sg = st2[row][0] + st2[row][2];
        float sx = st2[row][1] + st2[row][3];
        gz[r] = (64.f*gy[n][r] - sg - xh[n][r]*sx) * (rsv * (1.f/64.f));
      }
      store_pk4(&tG2[IDX(col, mtw*16+lg*4, 64)], gz[0],gz[1],gz[2],gz[3]);
    }
    __syncthreads();
    SB();

    // ---- S3: gZ1 = (gZ2 @ W2^T) * gelu_bwd(Z1); Z1 recomputed bit-identically
    {
      f4 acc3[8];
      #pragma unroll
      for (int t=0;t<8;++t) acc3[t] = ZV;
      #pragma unroll
      for (int kc=0; kc<2; ++kc){
        int k0 = kc*32 + lg*8;
        bf8 a;
        #pragma unroll
        for (int j=0;j<8;++j) a[j] = (short)tG2[IDX(k0+j, mtw*16+lr, 64)];
        #pragma unroll
        for (int t=0;t<8;++t){
          bf8 bb;
          #pragma unroll
          for (int j=0;j<8;++j) bb[j] = (short)tW2[IDX(k0+j, (nw*8+t)*16+lr, 256)];
          acc3[t] = MFMA16(a, bb, acc3[t]);
        }
      }
      SB();
      bf8 xk0 = *(const bf8*)&sXk[IDX(mtw*16+lr, 0*32+lg*8, 64)];
      bf8 xk1 = *(const bf8*)&sXk[IDX(mtw*16+lr, 1*32+lg*8, 64)];
      #pragma unroll
      for (int t=0;t<8;++t){
        int col = (nw*8+t)*16+lr;
        f4 z = ZV;
        z = MFMA16(xk0, *(const bf8*)&tW1[IDX(col, 0*32+lg*8, 64)], z);
        z = MFMA16(xk1, *(const bf8*)&tW1[IDX(col, 1*32+lg*8, 64)], z);
        float bias = b1f[col];
        float gv[4];
        #pragma unroll
        for (int r=0;r<4;++r) gv[r] = acc3[t][r] * gelu_bwd_f(z[r] + bias);
        store_pk4(&tG1[IDX(col, mtw*16+lg*4, 64)], gv[0],gv[1],gv[2],gv[3]);
      }
    }
    __syncthreads();
    SB();

    // ---- S5: Z1_bar = xq@W1(old) + M1@gZ1 + b1 ; pack X2_bar bf16 immediately
    sh4 X2bp[8];
    {
      f4 acc4[8];
      #pragma unroll
      for (int t=0;t<8;++t) acc4[t] = ZV;
      #pragma unroll
      for (int kc=0; kc<2; ++kc){
        bf8 a = kc ? aq1 : aq0;
        #pragma unroll
        for (int t=0;t<8;++t){
          bf8 bb = *(const bf8*)&tW1[IDX((nw*8+t)*16+lr, kc*32+lg*8, 64)];
          acc4[t] = MFMA16(a, bb, acc4[t]);
        }
      }
      #pragma unroll
      for (int kc=0; kc<2; ++kc){
        bf8 a = *(const bf8*)&sM[IDX(mtw*16+lr, kc*32+lg*8, 64)];
        #pragma unroll
        for (int t=0;t<8;++t){
          bf8 bb = *(const bf8*)&tG1[IDX((nw*8+t)*16+lr, kc*32+lg*8, 64)];
          acc4[t] = MFMA16(a, bb, acc4[t]);
        }
      }
      SB();
      #pragma unroll
      for (int t=0;t<8;++t){
        float bias = b1f[(nw*8+t)*16+lr];
        #pragma unroll
        for (int r=0;r<4;++r) X2bp[t][r] = (short)f2bf(gelu_f(acc4[t][r] + bias));
      }
    }
    SB();
    // ---- S6': W1n = tW1(old) + (-eta*xk)^T @ gZ1 ; b1 colsum via Et-broadcast MFMA
    f4 W1n[8]; float b1d[8];
    #pragma unroll
    for (int t=0;t<8;++t){
      sh4 cf = *(const sh4*)&tW1[IDX((nw*8+t)*16+lr, mtw*16+lg*4, 64)];
      #pragma unroll
      for (int r=0;r<4;++r) W1n[t][r] = bf2f((u16)cf[r]);
    }
    SB();
    #pragma unroll
    for (int kc=0; kc<2; ++kc){
      int k0 = kc*32 + lg*8;
      bfu XA, EA;
      #pragma unroll
      for (int jj=0;jj<4;++jj){
        float e0 = Et[k0+2*jj], e1 = Et[k0+2*jj+1];
        EA.u[jj] = pk2(e0, e1);
        XA.u[jj] = pk2(-bf2f(sXk[IDX(k0+2*jj,   mtw*16+lr, 64)]) * e0,
                       -bf2f(sXk[IDX(k0+2*jj+1, mtw*16+lr, 64)]) * e1);
      }
      #pragma unroll
      for (int t=0;t<8;++t){
        bf8 bb = *(const bf8*)&tG1[IDX((nw*8+t)*16+lr, kc*32+lg*8, 64)];
        W1n[t] = MFMA16(XA.v, bb, W1n[t]);
        f4 d0 = ZV;
        d0 = MFMA16(EA.v, bb, d0);
        if (kc==0) b1d[t] = d0[0]; else b1d[t] += d0[0];
      }
    }
    __syncthreads();
    SB();
    // commit new W1 (bf16), write X2_bar over tG1, apply b1 delta
    u16* X2b = tG1;
    #pragma unroll
    for (int t=0;t<8;++t){
      int col = (nw*8+t)*16+lr;
      #pragma unroll
      for (int r=0;r<4;++r)
        X2b[IDX(mtw*16+lg*4+r, col, 256)] = (u16)X2bp[t][r];
      store_pk4(&tW1[IDX(col, mtw*16+lg*4, 64)], W1n[t][0],W1n[t][1],W1n[t][2],W1n[t][3]);
    }
    if (mtw == 0 && lg == 0){
      #pragma unroll
      for (int t=0;t<8;++t) b1f[(nw*8+t)*16+lr] -= b1d[t];
    }
    __syncthreads();
    SB();

    // ---- S7: Attn2 -> M2
    {
      f4 accB[2];
      accB[0] = ZV; accB[1] = ZV;
      #pragma unroll
      for (int kc=0; kc<8; ++kc){
        bf8 a = *(const bf8*)&X2b[IDX(mtw*16+lr, kc*32+lg*8, 256)];
        #pragma unroll
        for (int n=0;n<2;++n){
          bf8 bb = *(const bf8*)&sX2[IDX((nw*2+n)*16+lr, kc*32+lg*8, 256)];
          accB[n] = MFMA16(a, bb, accB[n]);
        }
      }
      SB();
      #pragma unroll
      for (int n=0;n<2;++n){
        int col = (nw*2+n)*16+lr;
        float e = Et[col];
        #pragma unroll
        for (int r=0;r<4;++r){
          int row = mtw*16+lg*4+r;
          float m = (col <= row) ? (-e * (accB[n][r] + 1.f)) : 0.f;
          sM[IDX(row, col, 64)] = f2bf(m);
        }
      }
    }
    __syncthreads();
    SB();

    // ---- S8: Z2_bar = X2_bar@W2 + M2@gZ2 + b2 (acc6)
    f4 acc6[2];
    acc6[0] = ZV; acc6[1] = ZV;
    #pragma unroll
    for (int kc=0; kc<8; ++kc){
      bf8 a = *(const bf8*)&X2b[IDX(mtw*16+lr, kc*32+lg*8, 256)];
      #pragma unroll
      for (int n=0;n<2;++n){
        bf8 bb = *(const bf8*)&tW2[IDX((nw*2+n)*16+lr, kc*32+lg*8, 256)];
        acc6[n] = MFMA16(a, bb, acc6[n]);
      }
    }
    #pragma unroll
    for (int kc=0; kc<2; ++kc){
      bf8 a = *(const bf8*)&sM[IDX(mtw*16+lr, kc*32+lg*8, 64)];
      #pragma unroll
      for (int n=0;n<2;++n){
        bf8 bb = *(const bf8*)&tG2[IDX((nw*2+n)*16+lr, kc*32+lg*8, 64)];
        acc6[n] = MFMA16(a, bb, acc6[n]);
      }
    }
    SB();
    #pragma unroll
    for (int n=0;n<2;++n){
      float bias0 = b2f[(nw*2+n)*16+lr];
      #pragma unroll
      for (int r=0;r<4;++r) acc6[n][r] += bias0;
    }
    SB();
    // ---- S9': W2n = tW2(old) + (-eta*X2)^T @ gZ2 ; b2 colsum via Et-broadcast MFMA
    f4 W2n[8]; float b2d[2];
    #pragma unroll
    for (int t=0;t<8;++t){
      sh4 cf = *(const sh4*)&tW2[IDX((t>>1)*16+lr, (2*wid+(t&1))*16+lg*4, 256)];
      #pragma unroll
      for (int r=0;r<4;++r) W2n[t][r] = bf2f((u16)cf[r]);
    }
    SB();
    #pragma unroll
    for (int n=0;n<2;++n){
      f4 d = ZV;
      #pragma unroll
      for (int kc=0; kc<2; ++kc){
        int k0 = kc*32+lg*8;
        bfu EA;
        #pragma unroll
        for (int jj=0;jj<4;++jj) EA.u[jj] = pk2(Et[k0+2*jj], Et[k0+2*jj+1]);
        bf8 bb = *(const bf8*)&tG2[IDX((nw*2+n)*16+lr, kc*32+lg*8, 64)];
        d = MFMA16(EA.v, bb, d);
      }
      b2d[n] = d[0];
    }
    SB();
    #pragma unroll
    for (int kc=0; kc<2; ++kc){
      int k0 = kc*32 + lg*8;
      bfu A2[2];
      #pragma unroll
      for (int ta=0; ta<2; ++ta)
        #pragma unroll
        for (int jj=0;jj<4;++jj)
          A2[ta].u[jj] = pk2(-bf2f(sX2[IDX(k0+2*jj,   (2*wid+ta)*16+lr, 256)]) * Et[k0+2*jj],
                             -bf2f(sX2[IDX(k0+2*jj+1, (2*wid+ta)*16+lr, 256)]) * Et[k0+2*jj+1]);
      #pragma unroll
      for (int nb=0; nb<4; ++nb){
        bf8 bb = *(const bf8*)&tG2[IDX(nb*16+lr, kc*32+lg*8, 64)];
        #pragma unroll
        for (int ta=0; ta<2; ++ta) W2n[nb*2+ta] = MFMA16(A2[ta].v, bb, W2n[nb*2+ta]);
      }
    }
    __syncthreads();
    SB();
    // commit new W2, apply b2 delta, LN-fwd stats of Z2_bar
    #pragma unroll
    for (int t=0;t<8;++t)
      store_pk4(&tW2[IDX((t>>1)*16+lr, (2*wid+(t&1))*16+lg*4, 256)], W2n[t][0],W2n[t][1],W2n[t][2],W2n[t][3]);
    if (mtw == 0 && lg == 0){
      #pragma unroll
      for (int n=0;n<2;++n) b2f[(nw*2+n)*16+lr] -= b2d[n];
    }
    SB();
    {
      float ps[4], pq[4];
      #pragma unroll
      for (int r=0;r<4;++r){ ps[r]=0.f; pq[r]=0.f; }
      #pragma unroll
      for (int n=0;n<2;++n)
        #pragma unroll
        for (int r=0;r<4;++r){ ps[r] += acc6[n][r]; pq[r] += acc6[n][r]*acc6[n][r]; }
      #pragma unroll
      for (int r=0;r<4;++r)
        #pragma unroll
        for (int off=1; off<16; off<<=1){ ps[r] += __shfl_xor(ps[r], off); pq[r] += __shfl_xor(pq[r], off); }
      if (lr == 0){
        #pragma unroll
        for (int r=0;r<4;++r){ st1[mtw*16+lg*4+r][nw*2] = ps[r]; st1[mtw*16+lg*4+r][nw*2+1] = pq[r]; }
      }
    }
    __syncthreads();
    SB();
    // ---- S10: out = xq + ln_fwd(Z2_bar) (in place over target cols)
    #pragma unroll
    for (int r=0;r<4;++r){
      int row = mtw*16+lg*4+r;
      float s1 = st1[row][0] + st1[row][2];
      float s2 = st1[row][1] + st1[row][3];
      float m = s1 * (1.f/64.f);
      float rstd = rsqrtf(s2*(1.f/64.f) - m*m + 1e-6f);
      size_t ro = (size_t)row*3200;
      #pragma unroll
      for (int n=0;n<2;++n){
        int col = (nw*2+n)*16+lr;
        float val = bf2f(xq[ro+col]) + gwv[col]*(acc6[n][r]-m)*rstd + gbv[col];
        yrow[ro+col] = f2bf(val);
      }
    }
    __syncthreads();
  }
}

// ---------------------------------------------------------------- post layernorm over D=1024 (in place)
__global__ __launch_bounds__(256) void postln_kernel(u16* __restrict__ qkvl,
    const float* __restrict__ pw, const float* __restrict__ pb)
{
  int row = blockIdx.x;
  u16* rp = qkvl + (size_t)row*3200;
  float v[4]; float s1=0.f, s2=0.f;
  #pragma unroll
  for (int i=0;i<4;++i){ v[i] = bf2f(rp[2048 + threadIdx.x + i*256]); s1 += v[i]; s2 += v[i]*v[i]; }
  #pragma unroll
  for (int off=1; off<64; off<<=1){ s1 += __shfl_xor(s1, off); s2 += __shfl_xor(s2, off); }
  __shared__ float r1[4], r2[4];
  int w = threadIdx.x >> 6;
  if ((threadIdx.x & 63) == 0){ r1[w] = s1; r2[w] = s2; }
  __syncthreads();
  s1 = r1[0]+r1[1]+r1[2]+r1[3];
  s2 = r2[0]+r2[1]+r2[2]+r2[3];
  float mu = s1*(1.f/1024.f);
  float rstd = rsqrtf(s2*(1.f/1024.f) - mu*mu + 1e-6f);
  #pragma unroll
  for (int i=0;i<4;++i){
    int col = threadIdx.x + i*256;
    rp[col] = f2bf(pw[col]*(v[i]-mu)*rstd + pb[col]);
  }
}

// ---------------------------------------------------------------- launch
extern "C" void kernel_launch(void* const* d_in, const int* in_sizes, int n_in,
                              void* d_out, int out_size, void* d_ws, size_t ws_size,
                              hipStream_t stream)
{
  const float* x   = (const float*)d_in[0];
  const float* Wq  = (const float*)d_in[1];
  const float* Wk  = (const float*)d_in[2];
  const float* Wv  = (const float*)d_in[3];
  const float* Wo  = (const float*)d_in[4];
  const float* W1  = (const float*)d_in[5];
  const float* b1  = (const float*)d_in[6];
  const float* W2  = (const float*)d_in[7];
  const float* b2  = (const float*)d_in[8];
  const float* tnw = (const float*)d_in[9];
  const float* tnb = (const float*)d_in[10];
  const float* lrw = (const float*)d_in[11];
  const float* lrb = (const float*)d_in[12];
  const float* pnw = (const float*)d_in[13];
  const float* pnb = (const float*)d_in[14];
  (void)in_sizes; (void)n_in; (void)out_size; (void)ws_size;

  u16* qkvl  = (u16*)d_ws;                       // [8192][3200] bf16 = 50 MB
  u16* wcat  = (u16*)d_out;                      // d_out scratch; dead before final GEMM
  float* etg = (float*)((char*)d_out + 6553600);

  convert_kernel<<<1024, 256, 0, stream>>>(Wq, Wk, Wv, lrw, wcat);
  gemm_kernel<1,0,0><<<dim3(25, 64), 256, 0, stream>>>(x, wcat, qkvl, 8192, 3200, 1024, 1024, 1024, 3200);
  postproc_kernel<<<8192, 1024, 0, stream>>>(qkvl, tnw, tnb, lrb, etg);
  scan_kernel<<<64, 512, 0, stream>>>(qkvl, etg, W1, b1, W2, b2, tnw, tnb);
  postln_kernel<<<8192, 256, 0, stream>>>(qkvl, pnw, pnb);
  gemm_kernel<0,1,1><<<dim3(8, 64), 256, 0, stream>>>(qkvl, Wo, d_out, 8192, 1024, 1024, 3200, 1024, 1024);
}